// Round 2
// baseline (1848.904 us; speedup 1.0000x reference)
//
#include <hip/hip_runtime.h>

// Problem constants (from reference)
#define B_   32
#define Q_   40
#define L_   1024
#define H_   1024
#define QQ_  80            // 2*Q_ (start rows then end rows)
#define M_   1280          // B_*Q_
#define K3_  3072          // 3*H_

// Workspace layout (float offsets)
#define OFF_START 0
#define OFF_END   1280
#define OFF_TOS   2560
#define OFF_TOE   2592
#define OFF_WT    4096                      // [B][L][QQ]  fp32
#define OFF_FEAT  (OFF_WT + B_*L_*QQ_)      // [B][QQ][H]  fp32 (start rows 0..39, end rows 40..79)
#define OFF_HID   (OFF_FEAT + B_*QQ_*H_)    // [M][H]      fp32

// ---- txt_off: (B,H) @ (H,2), tanh, scale ----
__global__ void k_txt_off(const float* __restrict__ txt,
                          const float* __restrict__ pw,
                          const float* __restrict__ pb,
                          float* __restrict__ ws) {
    int b = blockIdx.x, tid = threadIdx.x;
    float s0 = 0.f, s1 = 0.f;
    for (int h = tid; h < H_; h += 256) {
        float t = txt[b * H_ + h];
        s0 += t * pw[2 * h + 0];
        s1 += t * pw[2 * h + 1];
    }
    __shared__ float r0[256], r1[256];
    r0[tid] = s0; r1[tid] = s1; __syncthreads();
    for (int off = 128; off > 0; off >>= 1) {
        if (tid < off) { r0[tid] += r0[tid + off]; r1[tid] += r1[tid + off]; }
        __syncthreads();
    }
    if (tid == 0) {
        // 0.5 * log(max(L*min_sig*4, 1+1e-6)) = 0.5*log(1.000001)
        const float half_lr = 4.9999975e-07f;
        ws[OFF_TOS + b] = tanhf(r0[0] + pb[0]) * half_lr;
        ws[OFF_TOE + b] = tanhf(r1[0] + pb[1]) * half_lr;
    }
}

// ---- initial start/end from pred_spans ----
__global__ void k_span_init(const float* __restrict__ spans,
                            float* __restrict__ ws) {
    int i = blockIdx.x * 256 + threadIdx.x;
    if (i < M_) {
        float c = spans[2 * i], w = spans[2 * i + 1];
        float s = fminf(fmaxf(c - 0.5f * w, 0.f), 1.f);
        float e = fminf(fmaxf(c + 0.5f * w, 0.f), 1.f);
        ws[OFF_START + i] = s;
        ws[OFF_END + i] = e;
    }
}

// ---- normalized Gaussian weights into wT[b][l][80] ----
__global__ void k_weights(const float* __restrict__ vmask,
                          const float* __restrict__ p_ls_s,
                          const float* __restrict__ p_ls_e,
                          const float* __restrict__ p_sw_s,
                          const float* __restrict__ p_sw_e,
                          float* __restrict__ ws) {
    int m = blockIdx.x;                 // bq
    int b = m / Q_, q = m - b * Q_;
    int tid = threadIdx.x;
    float s = ws[OFF_START + m], e = ws[OFF_END + m];
    float width = fmaxf(e - s, 1e-6f);
    const float min_sig = 1.0f / (4.0f * (float)L_);
    float sig_s = fmaxf(expf(p_ls_s[0] + p_sw_s[0] * width + ws[OFF_TOS + b]), min_sig);
    float sig_e = fmaxf(expf(p_ls_e[0] + p_sw_e[0] * width + ws[OFF_TOE + b]), min_sig);
    float inv_s = 1.0f / sig_s, inv_e = 1.0f / sig_e;

    float wsv[4], wev[4];
    float sumS = 0.f, sumE = 0.f;
    #pragma unroll
    for (int k = 0; k < 4; k++) {
        int l = tid + k * 256;
        float t = (float)l * (1.0f / 1023.0f);
        float mk = vmask[b * L_ + l];
        float ds = (t - s) * inv_s, de = (t - e) * inv_e;
        float a = expf(-0.5f * ds * ds) * mk;
        float c = expf(-0.5f * de * de) * mk;
        wsv[k] = a; wev[k] = c; sumS += a; sumE += c;
    }
    __shared__ float r0[256], r1[256];
    r0[tid] = sumS; r1[tid] = sumE; __syncthreads();
    for (int off = 128; off > 0; off >>= 1) {
        if (tid < off) { r0[tid] += r0[tid + off]; r1[tid] += r1[tid + off]; }
        __syncthreads();
    }
    float iS = 1.0f / fmaxf(r0[0], 1e-8f);
    float iE = 1.0f / fmaxf(r1[0], 1e-8f);
    float* wt = ws + OFF_WT + (size_t)b * L_ * QQ_;
    #pragma unroll
    for (int k = 0; k < 4; k++) {
        int l = tid + k * 256;
        wt[l * QQ_ + q]      = wsv[k] * iS;
        wt[l * QQ_ + Q_ + q] = wev[k] * iE;
    }
}

// ---- pool GEMM: feat[b][qq][n] = sum_l wT[b][l][qq] * vid[b][l][n] ----
// grid (B, H/256, 2); each block: 40 q-rows, 256 n-columns
__global__ __launch_bounds__(256) void k_pool(const float* __restrict__ vid,
                                              float* __restrict__ ws) {
    int b = blockIdx.x;
    int n = blockIdx.y * 256 + threadIdx.x;
    int qbase = blockIdx.z * Q_;
    int tid = threadIdx.x;
    __shared__ float wtile[32][40];     // 5 KB; rows 160B (16B aligned)
    const float* wt = ws + OFF_WT + (size_t)b * L_ * QQ_;
    float* feat = ws + OFF_FEAT + (size_t)b * QQ_ * H_;
    const float* vb = vid + (size_t)b * L_ * H_;

    float acc[40];
    #pragma unroll
    for (int j = 0; j < 40; j++) acc[j] = 0.f;

    for (int l0 = 0; l0 < L_; l0 += 32) {
        for (int idx = tid; idx < 32 * 40; idx += 256) {
            int i = idx / 40, j = idx - 40 * i;
            wtile[i][j] = wt[(l0 + i) * QQ_ + qbase + j];
        }
        __syncthreads();
        #pragma unroll 2
        for (int i = 0; i < 32; i++) {
            float v = vb[(size_t)(l0 + i) * H_ + n];
            const float4* wr = (const float4*)(&wtile[i][0]);   // broadcast reads
            #pragma unroll
            for (int j4 = 0; j4 < 10; j4++) {
                float4 w4 = wr[j4];
                acc[j4 * 4 + 0] += w4.x * v;
                acc[j4 * 4 + 1] += w4.y * v;
                acc[j4 * 4 + 2] += w4.z * v;
                acc[j4 * 4 + 3] += w4.w * v;
            }
        }
        __syncthreads();
    }
    #pragma unroll
    for (int j = 0; j < 40; j++)
        feat[(size_t)(qbase + j) * H_ + n] = acc[j];
}

// ---- MLP0: hidden = relu(joint @ w0 + b0); joint = [featS | featE | txt] ----
// grid (M/16, H/256); block 256 threads; 16 m-rows x 256 n-cols per block
__global__ __launch_bounds__(256) void k_mlp0(const float* __restrict__ txt,
                                              const float* __restrict__ w0,
                                              const float* __restrict__ b0,
                                              float* __restrict__ ws) {
    int m0 = blockIdx.x * 16;
    int n = blockIdx.y * 256 + threadIdx.x;
    int tid = threadIdx.x;
    __shared__ float jt[64][16];        // [k][m] layout, rows 64B aligned
    const float* feat = ws + OFF_FEAT;
    float acc[16];
    #pragma unroll
    for (int i = 0; i < 16; i++) acc[i] = 0.f;

    for (int kt = 0; kt < K3_; kt += 64) {
        for (int idx = tid; idx < 1024; idx += 256) {
            int kk = idx >> 4, mm = idx & 15;
            int m = m0 + mm, k = kt + kk;
            int b = m / Q_, q = m - b * Q_;
            float v;
            if (k < H_)          v = feat[((size_t)b * QQ_ + q) * H_ + k];
            else if (k < 2 * H_) v = feat[((size_t)b * QQ_ + Q_ + q) * H_ + (k - H_)];
            else                 v = txt[b * H_ + (k - 2 * H_)];
            jt[kk][mm] = v;
        }
        __syncthreads();
        #pragma unroll 4
        for (int kk = 0; kk < 64; kk++) {
            float wv = w0[(size_t)(kt + kk) * H_ + n];
            const float4* jr = (const float4*)(&jt[kk][0]);     // broadcast
            #pragma unroll
            for (int m4 = 0; m4 < 4; m4++) {
                float4 j4 = jr[m4];
                acc[m4 * 4 + 0] += j4.x * wv;
                acc[m4 * 4 + 1] += j4.y * wv;
                acc[m4 * 4 + 2] += j4.z * wv;
                acc[m4 * 4 + 3] += j4.w * wv;
            }
        }
        __syncthreads();
    }
    float bn = b0[n];
    float* hid = ws + OFF_HID;
    #pragma unroll
    for (int mm = 0; mm < 16; mm++)
        hid[(size_t)(m0 + mm) * H_ + n] = fmaxf(acc[mm] + bn, 0.f);
}

// ---- MLP1 + span update + outputs ----
__global__ void k_mlp1(const float* __restrict__ w1,
                       const float* __restrict__ b1,
                       float* __restrict__ ws,
                       float* __restrict__ out, int pass) {
    int m = blockIdx.x, tid = threadIdx.x;
    const float* hid = ws + OFF_HID + (size_t)m * H_;
    float p0 = 0.f, p1 = 0.f;
    for (int k = tid; k < H_; k += 256) {
        float h = hid[k];
        p0 += h * w1[2 * k + 0];
        p1 += h * w1[2 * k + 1];
    }
    __shared__ float r0[256], r1[256];
    r0[tid] = p0; r1[tid] = p1; __syncthreads();
    for (int off = 128; off > 0; off >>= 1) {
        if (tid < off) { r0[tid] += r0[tid + off]; r1[tid] += r1[tid + off]; }
        __syncthreads();
    }
    if (tid == 0) {
        float d0 = tanhf(r0[0] + b1[0]) * 0.1f;
        float d1 = tanhf(r1[0] + b1[1]) * 0.1f;
        float s = fminf(fmaxf(ws[OFF_START + m] + d0, 0.f), 1.f);
        float e = fminf(fmaxf(ws[OFF_END + m] + d1, 0.f), 1.f);
        ws[OFF_START + m] = s;
        ws[OFF_END + m] = e;
        float cen = 0.5f * (s + e);
        float wid = fmaxf(e - s, 1e-6f);
        // chunk 1: stacked passes at offset 2560
        out[2560 + (size_t)(pass * M_ + m) * 2 + 0] = cen;
        out[2560 + (size_t)(pass * M_ + m) * 2 + 1] = wid;
        // chunk 0: passes[-1]
        if (pass == 1) { out[2 * m + 0] = cen; out[2 * m + 1] = wid; }
    }
}

extern "C" void kernel_launch(void* const* d_in, const int* in_sizes, int n_in,
                              void* d_out, int out_size, void* d_ws, size_t ws_size,
                              hipStream_t stream) {
    const float* spans = (const float*)d_in[0];
    const float* vid   = (const float*)d_in[1];
    const float* vmask = (const float*)d_in[2];
    const float* txt   = (const float*)d_in[3];
    const float* ls_s  = (const float*)d_in[4];
    const float* ls_e  = (const float*)d_in[5];
    const float* sw_s  = (const float*)d_in[6];
    const float* sw_e  = (const float*)d_in[7];
    const float* pw    = (const float*)d_in[8];
    const float* pb    = (const float*)d_in[9];
    const float* w0    = (const float*)d_in[10];
    const float* b0    = (const float*)d_in[11];
    const float* w1    = (const float*)d_in[12];
    const float* b1    = (const float*)d_in[13];
    float* ws = (float*)d_ws;
    float* out = (float*)d_out;

    hipLaunchKernelGGL(k_txt_off, dim3(32), dim3(256), 0, stream, txt, pw, pb, ws);
    hipLaunchKernelGGL(k_span_init, dim3(5), dim3(256), 0, stream, spans, ws);
    for (int p = 0; p < 2; p++) {
        hipLaunchKernelGGL(k_weights, dim3(M_), dim3(256), 0, stream,
                           vmask, ls_s, ls_e, sw_s, sw_e, ws);
        hipLaunchKernelGGL(k_pool, dim3(B_, H_ / 256, 2), dim3(256), 0, stream, vid, ws);
        hipLaunchKernelGGL(k_mlp0, dim3(M_ / 16, H_ / 256), dim3(256), 0, stream,
                           txt, w0, b0, ws);
        hipLaunchKernelGGL(k_mlp1, dim3(M_), dim3(256), 0, stream, w1, b1, ws, out, p);
    }
}

// Round 3
// 577.660 us; speedup vs baseline: 3.2007x; 3.2007x over previous
//
#include <hip/hip_runtime.h>

// Problem constants
#define B_   32
#define Q_   40
#define L_   1024
#define H_   1024
#define QQ_  80
#define M_   1280          // B_*Q_
#define K3_  3072

// Workspace layout (BYTE offsets)
#define OB_VIDT  0u                              // bf16 [B][H][L]   67108864 B
#define OB_W0T   67108864u                       // bf16 [1024][3072] 6291456 B
#define OB_WT2   73400320u                       // bf16 [B][80][L]   5242880 B
#define OB_JOINT 78643200u                       // bf16 [M][3072]    7864320 B
#define OB_HID   86507520u                       // fp32 [M][1024]    5242880 B
#define OB_MISC  91750400u                       // fp32 misc (start/end/tos/toe)
// misc float offsets
#define MS_START 0
#define MS_END   1280
#define MS_TOS   2560
#define MS_TOE   2592

typedef short bf8 __attribute__((ext_vector_type(8)));   // 8 bf16 = 4 VGPRs
typedef float f4  __attribute__((ext_vector_type(4)));   // accumulator

static __device__ __forceinline__ unsigned short f2b(float f) {
    unsigned int x = __float_as_uint(f);
    unsigned int r = x + 0x7FFFu + ((x >> 16) & 1u);     // RNE
    return (unsigned short)(r >> 16);
}

// ---- txt_off: (B,H) @ (H,2), tanh, scale ----
__global__ void k_txt_off(const float* __restrict__ txt,
                          const float* __restrict__ pw,
                          const float* __restrict__ pb,
                          float* __restrict__ msc) {
    int b = blockIdx.x, tid = threadIdx.x;
    float s0 = 0.f, s1 = 0.f;
    for (int h = tid; h < H_; h += 256) {
        float t = txt[b * H_ + h];
        s0 += t * pw[2 * h + 0];
        s1 += t * pw[2 * h + 1];
    }
    __shared__ float r0[256], r1[256];
    r0[tid] = s0; r1[tid] = s1; __syncthreads();
    for (int off = 128; off > 0; off >>= 1) {
        if (tid < off) { r0[tid] += r0[tid + off]; r1[tid] += r1[tid + off]; }
        __syncthreads();
    }
    if (tid == 0) {
        const float half_lr = 4.9999975e-07f;   // 0.5*log(1.000001)
        msc[MS_TOS + b] = tanhf(r0[0] + pb[0]) * half_lr;
        msc[MS_TOE + b] = tanhf(r1[0] + pb[1]) * half_lr;
    }
}

// ---- initial start/end ----
__global__ void k_span_init(const float* __restrict__ spans,
                            float* __restrict__ msc) {
    int i = blockIdx.x * 256 + threadIdx.x;
    if (i < M_) {
        float c = spans[2 * i], w = spans[2 * i + 1];
        msc[MS_START + i] = fminf(fmaxf(c - 0.5f * w, 0.f), 1.f);
        msc[MS_END + i]   = fminf(fmaxf(c + 0.5f * w, 0.f), 1.f);
    }
}

// ---- transpose vid [B][L][H] fp32 -> vidT [B][H][L] bf16 ----
__global__ __launch_bounds__(256) void k_transpose_vid(const float* __restrict__ vid,
                                                       unsigned short* __restrict__ vidT) {
    __shared__ float tile[64][65];
    int b = blockIdx.x, l0 = blockIdx.y * 64, h0 = blockIdx.z * 64;
    int tx = threadIdx.x & 63, ty = threadIdx.x >> 6;
    const float* src = vid + ((size_t)b * L_ + l0) * H_ + h0;
    #pragma unroll
    for (int it = 0; it < 16; it++) {
        int li = it * 4 + ty;
        tile[li][tx] = src[(size_t)li * H_ + tx];
    }
    __syncthreads();
    int li2 = (threadIdx.x & 31) * 2, hy = threadIdx.x >> 5;
    #pragma unroll
    for (int it = 0; it < 8; it++) {
        int hi = it * 8 + hy;
        unsigned int u = (unsigned int)f2b(tile[li2][hi]) |
                         ((unsigned int)f2b(tile[li2 + 1][hi]) << 16);
        *(unsigned int*)(vidT + ((size_t)b * H_ + h0 + hi) * L_ + l0 + li2) = u;
    }
}

// ---- transpose w0 [3072][1024] fp32 -> w0T [1024][3072] bf16 ----
__global__ __launch_bounds__(256) void k_prep_w0t(const float* __restrict__ w0,
                                                  unsigned short* __restrict__ w0t) {
    __shared__ float tile[64][65];
    int k0 = blockIdx.x * 64, n0 = blockIdx.y * 64;
    int tx = threadIdx.x & 63, ty = threadIdx.x >> 6;
    #pragma unroll
    for (int it = 0; it < 16; it++) {
        int ki = it * 4 + ty;
        tile[ki][tx] = w0[(size_t)(k0 + ki) * H_ + n0 + tx];
    }
    __syncthreads();
    int ki2 = (threadIdx.x & 31) * 2, ny = threadIdx.x >> 5;
    #pragma unroll
    for (int it = 0; it < 8; it++) {
        int ni = it * 8 + ny;
        unsigned int u = (unsigned int)f2b(tile[ki2][ni]) |
                         ((unsigned int)f2b(tile[ki2 + 1][ni]) << 16);
        *(unsigned int*)(w0t + (size_t)(n0 + ni) * K3_ + k0 + ki2) = u;
    }
}

// ---- fill txt section of joint (cols 2048..3071), bf16 ----
__global__ void k_fill_txt(const float* __restrict__ txt,
                           unsigned short* __restrict__ joint) {
    int m = blockIdx.x, b = m / Q_;
    int h = threadIdx.x * 4;
    ushort4 v;
    v.x = f2b(txt[(size_t)b * H_ + h + 0]);
    v.y = f2b(txt[(size_t)b * H_ + h + 1]);
    v.z = f2b(txt[(size_t)b * H_ + h + 2]);
    v.w = f2b(txt[(size_t)b * H_ + h + 3]);
    *(ushort4*)(joint + (size_t)m * K3_ + 2048 + h) = v;
}

// ---- normalized Gaussian weights -> WT2 bf16 [b][qq][l] ----
__global__ void k_weights(const float* __restrict__ vmask,
                          const float* __restrict__ p_ls_s,
                          const float* __restrict__ p_ls_e,
                          const float* __restrict__ p_sw_s,
                          const float* __restrict__ p_sw_e,
                          const float* __restrict__ msc,
                          unsigned short* __restrict__ wt2) {
    int m = blockIdx.x;
    int b = m / Q_, q = m - b * Q_;
    int tid = threadIdx.x;
    float s = msc[MS_START + m], e = msc[MS_END + m];
    float width = fmaxf(e - s, 1e-6f);
    const float min_sig = 1.0f / (4.0f * (float)L_);
    float sig_s = fmaxf(expf(p_ls_s[0] + p_sw_s[0] * width + msc[MS_TOS + b]), min_sig);
    float sig_e = fmaxf(expf(p_ls_e[0] + p_sw_e[0] * width + msc[MS_TOE + b]), min_sig);
    float inv_s = 1.0f / sig_s, inv_e = 1.0f / sig_e;

    float wsv[4], wev[4], sumS = 0.f, sumE = 0.f;
    #pragma unroll
    for (int k = 0; k < 4; k++) {
        int l = tid + k * 256;
        float t = (float)l * (1.0f / 1023.0f);
        float mk = vmask[b * L_ + l];
        float ds = (t - s) * inv_s, de = (t - e) * inv_e;
        float a = expf(-0.5f * ds * ds) * mk;
        float c = expf(-0.5f * de * de) * mk;
        wsv[k] = a; wev[k] = c; sumS += a; sumE += c;
    }
    __shared__ float r0[256], r1[256];
    r0[tid] = sumS; r1[tid] = sumE; __syncthreads();
    for (int off = 128; off > 0; off >>= 1) {
        if (tid < off) { r0[tid] += r0[tid + off]; r1[tid] += r1[tid + off]; }
        __syncthreads();
    }
    float iS = 1.0f / fmaxf(r0[0], 1e-8f);
    float iE = 1.0f / fmaxf(r1[0], 1e-8f);
    unsigned short* wq = wt2 + ((size_t)b * QQ_ + q) * L_;
    unsigned short* we = wt2 + ((size_t)b * QQ_ + Q_ + q) * L_;
    #pragma unroll
    for (int k = 0; k < 4; k++) {
        int l = tid + k * 256;
        wq[l] = f2b(wsv[k] * iS);
        we[l] = f2b(wev[k] * iE);
    }
}

// ---- pool via MFMA: C[h,q] = sum_l vidT[h][l] * WT2[qq][l], write joint bf16 ----
// grid (B, 16); block 256 = 4 waves; wave: 16 h-rows x 80 q-cols (5 n-tiles)
__global__ __launch_bounds__(256) void k_pool_mfma(const unsigned short* __restrict__ vidT,
                                                   const unsigned short* __restrict__ wt2,
                                                   unsigned short* __restrict__ joint) {
    int b = blockIdx.x, ht = blockIdx.y;
    int wv = threadIdx.x >> 6, lane = threadIdx.x & 63;
    int ml = lane & 15, kg = lane >> 4;
    int hbase = ht * 64 + wv * 16;
    const unsigned short* ap = vidT + (((size_t)b * H_ + hbase + ml) * L_ + kg * 8);
    const unsigned short* bp = wt2 + (((size_t)b * QQ_ + ml) * L_ + kg * 8);
    f4 acc[5];
    #pragma unroll
    for (int t = 0; t < 5; t++) acc[t] = (f4){0.f, 0.f, 0.f, 0.f};

    #pragma unroll 2
    for (int l0 = 0; l0 < L_; l0 += 32) {
        bf8 a = *(const bf8*)(ap + l0);
        #pragma unroll
        for (int t = 0; t < 5; t++) {
            bf8 bb = *(const bf8*)(bp + (size_t)t * 16 * L_ + l0);
            acc[t] = __builtin_amdgcn_mfma_f32_16x16x32_bf16(a, bb, acc[t], 0, 0, 0);
        }
    }
    #pragma unroll
    for (int t = 0; t < 5; t++) {
        int qq = t * 16 + ml;
        int row = b * Q_ + (qq >= Q_ ? qq - Q_ : qq);
        int col = (qq >= Q_ ? H_ : 0) + hbase + kg * 4;
        ushort4 v;
        v.x = f2b(acc[t][0]); v.y = f2b(acc[t][1]);
        v.z = f2b(acc[t][2]); v.w = f2b(acc[t][3]);
        *(ushort4*)(joint + (size_t)row * K3_ + col) = v;
    }
}

// ---- MLP0 via MFMA: hid = relu(joint @ w0 + b0), fp32 out ----
// grid (20, 16); block 256 = 4 waves; block: 64 m x 64 n; wave: 16 m x 64 n
__global__ __launch_bounds__(256) void k_mlp0_mfma(const unsigned short* __restrict__ joint,
                                                   const unsigned short* __restrict__ w0t,
                                                   const float* __restrict__ b0,
                                                   float* __restrict__ hid) {
    int wv = threadIdx.x >> 6, lane = threadIdx.x & 63;
    int ml = lane & 15, kg = lane >> 4;
    int mbase = blockIdx.x * 64 + wv * 16;
    int nbase = blockIdx.y * 64;
    const unsigned short* ap = joint + ((size_t)(mbase + ml) * K3_ + kg * 8);
    const unsigned short* bp = w0t + ((size_t)(nbase + ml) * K3_ + kg * 8);
    f4 acc[4];
    #pragma unroll
    for (int t = 0; t < 4; t++) acc[t] = (f4){0.f, 0.f, 0.f, 0.f};

    #pragma unroll 2
    for (int k0 = 0; k0 < K3_; k0 += 32) {
        bf8 a = *(const bf8*)(ap + k0);
        #pragma unroll
        for (int t = 0; t < 4; t++) {
            bf8 bb = *(const bf8*)(bp + (size_t)t * 16 * K3_ + k0);
            acc[t] = __builtin_amdgcn_mfma_f32_16x16x32_bf16(a, bb, acc[t], 0, 0, 0);
        }
    }
    #pragma unroll
    for (int t = 0; t < 4; t++) {
        int n = nbase + t * 16 + ml;
        float bn = b0[n];
        #pragma unroll
        for (int r = 0; r < 4; r++) {
            int m = mbase + kg * 4 + r;
            hid[(size_t)m * H_ + n] = fmaxf(acc[t][r] + bn, 0.f);
        }
    }
}

// ---- MLP1 + span update + outputs ----
__global__ void k_mlp1(const float* __restrict__ w1,
                       const float* __restrict__ b1,
                       const float* __restrict__ hid,
                       float* __restrict__ msc,
                       float* __restrict__ out, int pass) {
    int m = blockIdx.x, tid = threadIdx.x;
    const float* hr = hid + (size_t)m * H_;
    float p0 = 0.f, p1 = 0.f;
    for (int k = tid; k < H_; k += 256) {
        float h = hr[k];
        p0 += h * w1[2 * k + 0];
        p1 += h * w1[2 * k + 1];
    }
    __shared__ float r0[256], r1[256];
    r0[tid] = p0; r1[tid] = p1; __syncthreads();
    for (int off = 128; off > 0; off >>= 1) {
        if (tid < off) { r0[tid] += r0[tid + off]; r1[tid] += r1[tid + off]; }
        __syncthreads();
    }
    if (tid == 0) {
        float d0 = tanhf(r0[0] + b1[0]) * 0.1f;
        float d1 = tanhf(r1[0] + b1[1]) * 0.1f;
        float s = fminf(fmaxf(msc[MS_START + m] + d0, 0.f), 1.f);
        float e = fminf(fmaxf(msc[MS_END + m] + d1, 0.f), 1.f);
        msc[MS_START + m] = s;
        msc[MS_END + m] = e;
        float cen = 0.5f * (s + e);
        float wid = fmaxf(e - s, 1e-6f);
        out[2560 + (size_t)(pass * M_ + m) * 2 + 0] = cen;
        out[2560 + (size_t)(pass * M_ + m) * 2 + 1] = wid;
        if (pass == 1) { out[2 * m + 0] = cen; out[2 * m + 1] = wid; }
    }
}

extern "C" void kernel_launch(void* const* d_in, const int* in_sizes, int n_in,
                              void* d_out, int out_size, void* d_ws, size_t ws_size,
                              hipStream_t stream) {
    const float* spans = (const float*)d_in[0];
    const float* vid   = (const float*)d_in[1];
    const float* vmask = (const float*)d_in[2];
    const float* txt   = (const float*)d_in[3];
    const float* ls_s  = (const float*)d_in[4];
    const float* ls_e  = (const float*)d_in[5];
    const float* sw_s  = (const float*)d_in[6];
    const float* sw_e  = (const float*)d_in[7];
    const float* pw    = (const float*)d_in[8];
    const float* pb    = (const float*)d_in[9];
    const float* w0    = (const float*)d_in[10];
    const float* b0    = (const float*)d_in[11];
    const float* w1    = (const float*)d_in[12];
    const float* b1    = (const float*)d_in[13];
    char* wsb = (char*)d_ws;
    unsigned short* vidT  = (unsigned short*)(wsb + OB_VIDT);
    unsigned short* w0t   = (unsigned short*)(wsb + OB_W0T);
    unsigned short* wt2   = (unsigned short*)(wsb + OB_WT2);
    unsigned short* joint = (unsigned short*)(wsb + OB_JOINT);
    float* hid = (float*)(wsb + OB_HID);
    float* msc = (float*)(wsb + OB_MISC);
    float* out = (float*)d_out;

    hipLaunchKernelGGL(k_txt_off, dim3(B_), dim3(256), 0, stream, txt, pw, pb, msc);
    hipLaunchKernelGGL(k_span_init, dim3(5), dim3(256), 0, stream, spans, msc);
    hipLaunchKernelGGL(k_transpose_vid, dim3(B_, 16, 16), dim3(256), 0, stream, vid, vidT);
    hipLaunchKernelGGL(k_prep_w0t, dim3(48, 16), dim3(256), 0, stream, w0, w0t);
    hipLaunchKernelGGL(k_fill_txt, dim3(M_), dim3(256), 0, stream, txt, joint);
    for (int p = 0; p < 2; p++) {
        hipLaunchKernelGGL(k_weights, dim3(M_), dim3(256), 0, stream,
                           vmask, ls_s, ls_e, sw_s, sw_e, msc, wt2);
        hipLaunchKernelGGL(k_pool_mfma, dim3(B_, 16), dim3(256), 0, stream, vidT, wt2, joint);
        hipLaunchKernelGGL(k_mlp0_mfma, dim3(20, 16), dim3(256), 0, stream, joint, w0t, b0, hid);
        hipLaunchKernelGGL(k_mlp1, dim3(M_), dim3(256), 0, stream, w1, b1, hid, msc, out, p);
    }
}

// Round 4
// 495.577 us; speedup vs baseline: 3.7308x; 1.1656x over previous
//
#include <hip/hip_runtime.h>

// Problem constants
#define B_   32
#define Q_   40
#define L_   1024
#define H_   1024
#define QQ_  80
#define M_   1280          // B_*Q_
#define K3_  3072

// Workspace layout (BYTE offsets)
#define OB_VIDT  0u                              // bf16 [B][H][L]    67108864 B
#define OB_W0T   67108864u                       // bf16 [1024][3072]  6291456 B
#define OB_WT2   73400320u                       // bf16 [B][80][L]    5242880 B
#define OB_JOINT 78643200u                       // bf16 [M][3072]     7864320 B
#define OB_PART  86507520u                       // bf16 [4][M][1024] 10485760 B
#define OB_MISC  96993280u                       // fp32 misc
// misc float offsets
#define MS_START 0
#define MS_END   1280
#define MS_TOS   2560
#define MS_TOE   2592

typedef short bf8 __attribute__((ext_vector_type(8)));   // 8 bf16 = 4 VGPRs
typedef float f4  __attribute__((ext_vector_type(4)));   // accumulator

static __device__ __forceinline__ unsigned short f2b(float f) {
    unsigned int x = __float_as_uint(f);
    unsigned int r = x + 0x7FFFu + ((x >> 16) & 1u);     // RNE
    return (unsigned short)(r >> 16);
}
static __device__ __forceinline__ float blo(unsigned int u) {
    return __uint_as_float(u << 16);
}
static __device__ __forceinline__ float bhi(unsigned int u) {
    return __uint_as_float(u & 0xffff0000u);
}

// ---- txt_off: (B,H) @ (H,2), tanh, scale ----
__global__ void k_txt_off(const float* __restrict__ txt,
                          const float* __restrict__ pw,
                          const float* __restrict__ pb,
                          float* __restrict__ msc) {
    int b = blockIdx.x, tid = threadIdx.x;
    float s0 = 0.f, s1 = 0.f;
    for (int h = tid; h < H_; h += 256) {
        float t = txt[b * H_ + h];
        s0 += t * pw[2 * h + 0];
        s1 += t * pw[2 * h + 1];
    }
    __shared__ float r0[256], r1[256];
    r0[tid] = s0; r1[tid] = s1; __syncthreads();
    for (int off = 128; off > 0; off >>= 1) {
        if (tid < off) { r0[tid] += r0[tid + off]; r1[tid] += r1[tid + off]; }
        __syncthreads();
    }
    if (tid == 0) {
        const float half_lr = 4.9999975e-07f;   // 0.5*log(1.000001)
        msc[MS_TOS + b] = tanhf(r0[0] + pb[0]) * half_lr;
        msc[MS_TOE + b] = tanhf(r1[0] + pb[1]) * half_lr;
    }
}

// ---- initial start/end ----
__global__ void k_span_init(const float* __restrict__ spans,
                            float* __restrict__ msc) {
    int i = blockIdx.x * 256 + threadIdx.x;
    if (i < M_) {
        float c = spans[2 * i], w = spans[2 * i + 1];
        msc[MS_START + i] = fminf(fmaxf(c - 0.5f * w, 0.f), 1.f);
        msc[MS_END + i]   = fminf(fmaxf(c + 0.5f * w, 0.f), 1.f);
    }
}

// ---- generic transpose+convert: src fp32 [..R..][C] -> dst bf16 [C][R] ----
// grid (R/64, C/64, batch); block 256
__global__ __launch_bounds__(256) void k_t32to16(const float* __restrict__ src,
                                                 unsigned short* __restrict__ dst,
                                                 int C, int R,
                                                 unsigned long long srcBatch,
                                                 unsigned long long dstBatch) {
    __shared__ float tile[64][68];
    int r0 = blockIdx.x * 64, c0 = blockIdx.y * 64;
    const float* s = src + (size_t)blockIdx.z * srcBatch + (size_t)r0 * C + c0;
    unsigned short* d = dst + (size_t)blockIdx.z * dstBatch;
    int t = threadIdx.x;
    int col4 = (t & 15) * 4, row = t >> 4;
    #pragma unroll
    for (int it = 0; it < 4; it++) {
        int r = it * 16 + row;
        float4 v = *(const float4*)(s + (size_t)r * C + col4);
        *(float4*)(&tile[r][col4]) = v;
    }
    __syncthreads();
    #pragma unroll
    for (int it = 0; it < 2; it++) {
        int slot = it * 256 + t;
        int c = slot & 63, lo = slot >> 6;      // lo: which l-octet
        int r = lo * 8;
        uint4 vv;
        vv.x = (unsigned int)f2b(tile[r + 0][c]) | ((unsigned int)f2b(tile[r + 1][c]) << 16);
        vv.y = (unsigned int)f2b(tile[r + 2][c]) | ((unsigned int)f2b(tile[r + 3][c]) << 16);
        vv.z = (unsigned int)f2b(tile[r + 4][c]) | ((unsigned int)f2b(tile[r + 5][c]) << 16);
        vv.w = (unsigned int)f2b(tile[r + 6][c]) | ((unsigned int)f2b(tile[r + 7][c]) << 16);
        *(uint4*)(d + (size_t)(c0 + c) * R + r0 + r) = vv;
    }
}

// ---- fill txt section of joint (cols 2048..3071), bf16 ----
__global__ void k_fill_txt(const float* __restrict__ txt,
                           unsigned short* __restrict__ joint) {
    int m = blockIdx.x, b = m / Q_;
    int h = threadIdx.x * 4;
    ushort4 v;
    v.x = f2b(txt[(size_t)b * H_ + h + 0]);
    v.y = f2b(txt[(size_t)b * H_ + h + 1]);
    v.z = f2b(txt[(size_t)b * H_ + h + 2]);
    v.w = f2b(txt[(size_t)b * H_ + h + 3]);
    *(ushort4*)(joint + (size_t)m * K3_ + 2048 + h) = v;
}

// ---- normalized Gaussian weights -> WT2 bf16 [b][qq][l] ----
__global__ void k_weights(const float* __restrict__ vmask,
                          const float* __restrict__ p_ls_s,
                          const float* __restrict__ p_ls_e,
                          const float* __restrict__ p_sw_s,
                          const float* __restrict__ p_sw_e,
                          const float* __restrict__ msc,
                          unsigned short* __restrict__ wt2) {
    int m = blockIdx.x;
    int b = m / Q_, q = m - b * Q_;
    int tid = threadIdx.x;
    float s = msc[MS_START + m], e = msc[MS_END + m];
    float width = fmaxf(e - s, 1e-6f);
    const float min_sig = 1.0f / (4.0f * (float)L_);
    float sig_s = fmaxf(expf(p_ls_s[0] + p_sw_s[0] * width + msc[MS_TOS + b]), min_sig);
    float sig_e = fmaxf(expf(p_ls_e[0] + p_sw_e[0] * width + msc[MS_TOE + b]), min_sig);
    float inv_s = 1.0f / sig_s, inv_e = 1.0f / sig_e;

    float wsv[4], wev[4], sumS = 0.f, sumE = 0.f;
    #pragma unroll
    for (int k = 0; k < 4; k++) {
        int l = tid + k * 256;
        float t = (float)l * (1.0f / 1023.0f);
        float mk = vmask[b * L_ + l];
        float ds = (t - s) * inv_s, de = (t - e) * inv_e;
        float a = expf(-0.5f * ds * ds) * mk;
        float c = expf(-0.5f * de * de) * mk;
        wsv[k] = a; wev[k] = c; sumS += a; sumE += c;
    }
    __shared__ float r0[256], r1[256];
    r0[tid] = sumS; r1[tid] = sumE; __syncthreads();
    for (int off = 128; off > 0; off >>= 1) {
        if (tid < off) { r0[tid] += r0[tid + off]; r1[tid] += r1[tid + off]; }
        __syncthreads();
    }
    float iS = 1.0f / fmaxf(r0[0], 1e-8f);
    float iE = 1.0f / fmaxf(r1[0], 1e-8f);
    unsigned short* wq = wt2 + ((size_t)b * QQ_ + q) * L_;
    unsigned short* we = wt2 + ((size_t)b * QQ_ + Q_ + q) * L_;
    #pragma unroll
    for (int k = 0; k < 4; k++) {
        int l = tid + k * 256;
        wq[l] = f2b(wsv[k] * iS);
        we[l] = f2b(wev[k] * iE);
    }
}

// ---- pool via MFMA, in-block L-split x2 ----
// grid (B, 16); block 512 = 8 waves: wave = (hsub 0..3, half 0..1)
// wave computes 16 h-rows x 80 q over one L-half; halves combined via LDS
__global__ __launch_bounds__(512) void k_pool_mfma(const unsigned short* __restrict__ vidT,
                                                   const unsigned short* __restrict__ wt2,
                                                   unsigned short* __restrict__ joint) {
    int b = blockIdx.x, ht = blockIdx.y;
    int wv = threadIdx.x >> 6, lane = threadIdx.x & 63;
    int hsub = wv & 3, half = wv >> 2;
    int ml = lane & 15, kg = lane >> 4;
    int hbase = ht * 64 + hsub * 16;
    const unsigned short* ap = vidT + (((size_t)b * H_ + hbase + ml) * L_ + half * 512 + kg * 8);
    const unsigned short* bp = wt2 + (((size_t)b * QQ_ + ml) * L_ + half * 512 + kg * 8);
    f4 acc[5];
    #pragma unroll
    for (int t = 0; t < 5; t++) acc[t] = (f4){0.f, 0.f, 0.f, 0.f};

    #pragma unroll 2
    for (int l0 = 0; l0 < 512; l0 += 32) {
        bf8 a = *(const bf8*)(ap + l0);
        #pragma unroll
        for (int t = 0; t < 5; t++) {
            bf8 bb = *(const bf8*)(bp + (size_t)t * 16 * L_ + l0);
            acc[t] = __builtin_amdgcn_mfma_f32_16x16x32_bf16(a, bb, acc[t], 0, 0, 0);
        }
    }

    __shared__ float cmb[4][5][64][4];          // 20 KB
    if (half == 1) {
        #pragma unroll
        for (int t = 0; t < 5; t++) {
            *(f4*)(&cmb[hsub][t][lane][0]) = acc[t];
        }
    }
    __syncthreads();
    if (half == 0) {
        #pragma unroll
        for (int t = 0; t < 5; t++) {
            f4 o = *(const f4*)(&cmb[hsub][t][lane][0]);
            acc[t] += o;
            int qq = t * 16 + ml;
            int row = b * Q_ + (qq >= Q_ ? qq - Q_ : qq);
            int col = (qq >= Q_ ? H_ : 0) + hbase + kg * 4;
            ushort4 v;
            v.x = f2b(acc[t][0]); v.y = f2b(acc[t][1]);
            v.z = f2b(acc[t][2]); v.w = f2b(acc[t][3]);
            *(ushort4*)(joint + (size_t)row * K3_ + col) = v;
        }
    }
}

// ---- MLP0 via MFMA, K-split x4 -> bf16 partials ----
// grid (20, 16, 4); block 256 = 4 waves; wave: 16 m x 64 n, k-range 768
__global__ __launch_bounds__(256) void k_mlp0_mfma(const unsigned short* __restrict__ joint,
                                                   const unsigned short* __restrict__ w0t,
                                                   unsigned short* __restrict__ part) {
    int wv = threadIdx.x >> 6, lane = threadIdx.x & 63;
    int ml = lane & 15, kg = lane >> 4;
    int mbase = blockIdx.x * 64 + wv * 16;
    int nbase = blockIdx.y * 64;
    int kbase = blockIdx.z * 768;
    const unsigned short* ap = joint + ((size_t)(mbase + ml) * K3_ + kbase + kg * 8);
    const unsigned short* bp = w0t + ((size_t)(nbase + ml) * K3_ + kbase + kg * 8);
    f4 acc[4];
    #pragma unroll
    for (int t = 0; t < 4; t++) acc[t] = (f4){0.f, 0.f, 0.f, 0.f};

    #pragma unroll 2
    for (int k0 = 0; k0 < 768; k0 += 32) {
        bf8 a = *(const bf8*)(ap + k0);
        #pragma unroll
        for (int t = 0; t < 4; t++) {
            bf8 bb = *(const bf8*)(bp + (size_t)t * 16 * K3_ + k0);
            acc[t] = __builtin_amdgcn_mfma_f32_16x16x32_bf16(a, bb, acc[t], 0, 0, 0);
        }
    }
    unsigned short* pp = part + (size_t)blockIdx.z * M_ * H_;
    #pragma unroll
    for (int t = 0; t < 4; t++) {
        int n = nbase + t * 16 + ml;
        #pragma unroll
        for (int r = 0; r < 4; r++) {
            int m = mbase + kg * 4 + r;
            pp[(size_t)m * H_ + n] = f2b(acc[t][r]);
        }
    }
}

// ---- MLP1: sum partials + bias + relu, dot w1, span update, outputs ----
__global__ void k_mlp1(const float* __restrict__ w1,
                       const float* __restrict__ b0,
                       const float* __restrict__ b1,
                       const unsigned short* __restrict__ part,
                       float* __restrict__ msc,
                       float* __restrict__ out, int pass) {
    int m = blockIdx.x, tid = threadIdx.x;
    float p0 = 0.f, p1 = 0.f;
    for (int k = tid * 2; k < H_; k += 512) {
        float h0 = b0[k], h1 = b0[k + 1];
        #pragma unroll
        for (int z = 0; z < 4; z++) {
            unsigned int u = *(const unsigned int*)(part + (size_t)z * M_ * H_ + (size_t)m * H_ + k);
            h0 += blo(u); h1 += bhi(u);
        }
        h0 = fmaxf(h0, 0.f); h1 = fmaxf(h1, 0.f);
        float2 wa = *(const float2*)(w1 + 2 * k);
        float2 wb = *(const float2*)(w1 + 2 * (k + 1));
        p0 += h0 * wa.x + h1 * wb.x;
        p1 += h0 * wa.y + h1 * wb.y;
    }
    __shared__ float r0[256], r1[256];
    r0[tid] = p0; r1[tid] = p1; __syncthreads();
    for (int off = 128; off > 0; off >>= 1) {
        if (tid < off) { r0[tid] += r0[tid + off]; r1[tid] += r1[tid + off]; }
        __syncthreads();
    }
    if (tid == 0) {
        float d0 = tanhf(r0[0] + b1[0]) * 0.1f;
        float d1 = tanhf(r1[0] + b1[1]) * 0.1f;
        float s = fminf(fmaxf(msc[MS_START + m] + d0, 0.f), 1.f);
        float e = fminf(fmaxf(msc[MS_END + m] + d1, 0.f), 1.f);
        msc[MS_START + m] = s;
        msc[MS_END + m] = e;
        float cen = 0.5f * (s + e);
        float wid = fmaxf(e - s, 1e-6f);
        out[2560 + (size_t)(pass * M_ + m) * 2 + 0] = cen;
        out[2560 + (size_t)(pass * M_ + m) * 2 + 1] = wid;
        if (pass == 1) { out[2 * m + 0] = cen; out[2 * m + 1] = wid; }
    }
}

extern "C" void kernel_launch(void* const* d_in, const int* in_sizes, int n_in,
                              void* d_out, int out_size, void* d_ws, size_t ws_size,
                              hipStream_t stream) {
    const float* spans = (const float*)d_in[0];
    const float* vid   = (const float*)d_in[1];
    const float* vmask = (const float*)d_in[2];
    const float* txt   = (const float*)d_in[3];
    const float* ls_s  = (const float*)d_in[4];
    const float* ls_e  = (const float*)d_in[5];
    const float* sw_s  = (const float*)d_in[6];
    const float* sw_e  = (const float*)d_in[7];
    const float* pw    = (const float*)d_in[8];
    const float* pb    = (const float*)d_in[9];
    const float* w0    = (const float*)d_in[10];
    const float* b0    = (const float*)d_in[11];
    const float* w1    = (const float*)d_in[12];
    const float* b1    = (const float*)d_in[13];
    char* wsb = (char*)d_ws;
    unsigned short* vidT  = (unsigned short*)(wsb + OB_VIDT);
    unsigned short* w0t   = (unsigned short*)(wsb + OB_W0T);
    unsigned short* wt2   = (unsigned short*)(wsb + OB_WT2);
    unsigned short* joint = (unsigned short*)(wsb + OB_JOINT);
    unsigned short* part  = (unsigned short*)(wsb + OB_PART);
    float* msc = (float*)(wsb + OB_MISC);
    float* out = (float*)d_out;

    hipLaunchKernelGGL(k_txt_off, dim3(B_), dim3(256), 0, stream, txt, pw, pb, msc);
    hipLaunchKernelGGL(k_span_init, dim3(5), dim3(256), 0, stream, spans, msc);
    // vid [B][L][H] -> vidT [B][H][L]
    hipLaunchKernelGGL(k_t32to16, dim3(16, 16, B_), dim3(256), 0, stream,
                       vid, vidT, H_, L_, (unsigned long long)L_ * H_, (unsigned long long)H_ * L_);
    // w0 [3072][1024] -> w0t [1024][3072]
    hipLaunchKernelGGL(k_t32to16, dim3(48, 16, 1), dim3(256), 0, stream,
                       w0, w0t, H_, K3_, 0ull, 0ull);
    hipLaunchKernelGGL(k_fill_txt, dim3(M_), dim3(256), 0, stream, txt, joint);
    for (int p = 0; p < 2; p++) {
        hipLaunchKernelGGL(k_weights, dim3(M_), dim3(256), 0, stream,
                           vmask, ls_s, ls_e, sw_s, sw_e, msc, wt2);
        hipLaunchKernelGGL(k_pool_mfma, dim3(B_, 16), dim3(512), 0, stream, vidT, wt2, joint);
        hipLaunchKernelGGL(k_mlp0_mfma, dim3(20, 16, 4), dim3(256), 0, stream, joint, w0t, part);
        hipLaunchKernelGGL(k_mlp1, dim3(M_), dim3(256), 0, stream, w1, b0, b1, part, msc, out, p);
    }
}

// Round 5
// 454.026 us; speedup vs baseline: 4.0722x; 1.0915x over previous
//
#include <hip/hip_runtime.h>

// Problem constants
#define B_   32
#define Q_   40
#define L_   1024
#define H_   1024
#define QQ_  80
#define M_   1280          // B_*Q_
#define K3_  3072
#define JK_  2048          // joint now holds only the two pooled-feature thirds

// Workspace layout (BYTE offsets)
#define OB_VIDT  0u                              // bf16 [B][H][L]    67108864
#define OB_W0T   67108864u                       // bf16 [1024][3072]  6291456
#define OB_WT2   73400320u                       // bf16 [B][80][L]    5242880
#define OB_JOINT 78643200u                       // bf16 [M][2048]     5242880
#define OB_PART  83886080u                       // bf16 [4][M][1024] 10485760
#define OB_TXTB  94371840u                       // bf16 [32][1024]      65536
#define OB_TXTP  94437376u                       // bf16 [4][32][1024]  262144
#define OB_MISC  94699520u                       // fp32 misc
// misc float offsets
#define MS_START 0
#define MS_END   1280
#define MS_TOS   2560
#define MS_TOE   2592

typedef short bf8 __attribute__((ext_vector_type(8)));   // 8 bf16 = 4 VGPRs
typedef float f4  __attribute__((ext_vector_type(4)));   // accumulator

static __device__ __forceinline__ unsigned short f2b(float f) {
    unsigned int x = __float_as_uint(f);
    unsigned int r = x + 0x7FFFu + ((x >> 16) & 1u);     // RNE
    return (unsigned short)(r >> 16);
}
static __device__ __forceinline__ float b2f16(unsigned short u) {
    return __uint_as_float((unsigned int)u << 16);
}
static __device__ __forceinline__ float blo(unsigned int u) {
    return __uint_as_float(u << 16);
}
static __device__ __forceinline__ float bhi(unsigned int u) {
    return __uint_as_float(u & 0xffff0000u);
}

// ---- prologue: txt_off (b<32) + txt->bf16 + span_init (bid 32..36) ----
__global__ __launch_bounds__(256) void k_prologue(const float* __restrict__ txt,
                                                  const float* __restrict__ pw,
                                                  const float* __restrict__ pb,
                                                  const float* __restrict__ spans,
                                                  unsigned short* __restrict__ txtb,
                                                  float* __restrict__ msc) {
    int bid = blockIdx.x, tid = threadIdx.x;
    if (bid < B_) {
        int b = bid;
        int h4 = tid * 4;
        float4 tv = *(const float4*)(txt + (size_t)b * H_ + h4);
        float4 pa = *(const float4*)(pw + 2 * h4);
        float4 pc = *(const float4*)(pw + 2 * h4 + 4);
        float s0 = tv.x * pa.x + tv.y * pa.z + tv.z * pc.x + tv.w * pc.z;
        float s1 = tv.x * pa.y + tv.y * pa.w + tv.z * pc.y + tv.w * pc.w;
        ushort4 o;
        o.x = f2b(tv.x); o.y = f2b(tv.y); o.z = f2b(tv.z); o.w = f2b(tv.w);
        *(ushort4*)(txtb + (size_t)b * H_ + h4) = o;
        __shared__ float r0[256], r1[256];
        r0[tid] = s0; r1[tid] = s1; __syncthreads();
        for (int off = 128; off > 0; off >>= 1) {
            if (tid < off) { r0[tid] += r0[tid + off]; r1[tid] += r1[tid + off]; }
            __syncthreads();
        }
        if (tid == 0) {
            const float half_lr = 4.9999975e-07f;   // 0.5*log(1.000001)
            msc[MS_TOS + b] = tanhf(r0[0] + pb[0]) * half_lr;
            msc[MS_TOE + b] = tanhf(r1[0] + pb[1]) * half_lr;
        }
    } else {
        int i = (bid - B_) * 256 + tid;
        if (i < M_) {
            float c = spans[2 * i], w = spans[2 * i + 1];
            msc[MS_START + i] = fminf(fmaxf(c - 0.5f * w, 0.f), 1.f);
            msc[MS_END + i]   = fminf(fmaxf(c + 0.5f * w, 0.f), 1.f);
        }
    }
}

// ---- combined transpose+convert: z<32 -> vid chunk, z>=32 -> w0 chunk ----
// per batch: src fp32 [64r x 64c tile of [R][C]] -> dst bf16 [c][r] with row stride
__global__ __launch_bounds__(256) void k_t32to16(const float* __restrict__ vid,
                                                 unsigned short* __restrict__ vidT,
                                                 const float* __restrict__ w0,
                                                 unsigned short* __restrict__ w0t) {
    __shared__ float tile[64][68];
    int z = blockIdx.z;
    const float* s;
    unsigned short* d;
    int dstRowStride;
    if (z < B_) {           // vid [B][L][H] -> vidT [B][H][L]
        s = vid + (size_t)z * L_ * H_;
        d = vidT + (size_t)z * H_ * L_;
        dstRowStride = L_;
    } else {                // w0 [3072][1024] -> w0t [1024][3072], 3 chunks of 1024 rows
        int zz = z - B_;
        s = w0 + (size_t)zz * 1024 * H_;
        d = w0t + (size_t)zz * 1024;
        dstRowStride = K3_;
    }
    int r0 = blockIdx.x * 64, c0 = blockIdx.y * 64;
    int t = threadIdx.x;
    int col4 = (t & 15) * 4, row = t >> 4;
    #pragma unroll
    for (int it = 0; it < 4; it++) {
        int r = it * 16 + row;
        float4 v = *(const float4*)(s + (size_t)(r0 + r) * 1024 + c0 + col4);
        *(float4*)(&tile[r][col4]) = v;
    }
    __syncthreads();
    #pragma unroll
    for (int it = 0; it < 2; it++) {
        int slot = it * 256 + t;
        int c = slot & 63, lo = slot >> 6;
        int r = lo * 8;
        uint4 vv;
        vv.x = (unsigned int)f2b(tile[r + 0][c]) | ((unsigned int)f2b(tile[r + 1][c]) << 16);
        vv.y = (unsigned int)f2b(tile[r + 2][c]) | ((unsigned int)f2b(tile[r + 3][c]) << 16);
        vv.z = (unsigned int)f2b(tile[r + 4][c]) | ((unsigned int)f2b(tile[r + 5][c]) << 16);
        vv.w = (unsigned int)f2b(tile[r + 6][c]) | ((unsigned int)f2b(tile[r + 7][c]) << 16);
        *(uint4*)(d + (size_t)(c0 + c) * dstRowStride + r0 + r) = vv;
    }
}

// ---- once: txtpart[z][b][n] = sum_{k in z-range} txtb[b][k] * w0[2048+k][n] ----
// grid (16, 2, 4); block 256 = 4 waves; wave: 16m x 16n, K-range 256
__global__ __launch_bounds__(256) void k_txt_mlp0(const unsigned short* __restrict__ txtb,
                                                  const unsigned short* __restrict__ w0t,
                                                  unsigned short* __restrict__ txtp) {
    int wv = threadIdx.x >> 6, lane = threadIdx.x & 63;
    int ml = lane & 15, kg = lane >> 4;
    int mbase = blockIdx.y * 16;
    int nbase = blockIdx.x * 64 + wv * 16;
    int kz = blockIdx.z * 256;
    const unsigned short* ap = txtb + ((size_t)(mbase + ml) * H_ + kz + kg * 8);
    const unsigned short* bp = w0t + ((size_t)(nbase + ml) * K3_ + JK_ + kz + kg * 8);
    f4 acc = (f4){0.f, 0.f, 0.f, 0.f};
    #pragma unroll
    for (int k0 = 0; k0 < 256; k0 += 32) {
        bf8 a = *(const bf8*)(ap + k0);
        bf8 bb = *(const bf8*)(bp + k0);
        acc = __builtin_amdgcn_mfma_f32_16x16x32_bf16(a, bb, acc, 0, 0, 0);
    }
    unsigned short* pp = txtp + (size_t)blockIdx.z * B_ * H_;
    int n = nbase + ml;
    #pragma unroll
    for (int r = 0; r < 4; r++) {
        int m = mbase + kg * 4 + r;
        pp[(size_t)m * H_ + n] = f2b(acc[r]);
    }
}

// ---- normalized Gaussian weights -> WT2 bf16 [b][qq][l] ----
__global__ void k_weights(const float* __restrict__ vmask,
                          const float* __restrict__ p_ls_s,
                          const float* __restrict__ p_ls_e,
                          const float* __restrict__ p_sw_s,
                          const float* __restrict__ p_sw_e,
                          const float* __restrict__ msc,
                          unsigned short* __restrict__ wt2) {
    int m = blockIdx.x;
    int b = m / Q_, q = m - b * Q_;
    int tid = threadIdx.x;
    float s = msc[MS_START + m], e = msc[MS_END + m];
    float width = fmaxf(e - s, 1e-6f);
    const float min_sig = 1.0f / (4.0f * (float)L_);
    float sig_s = fmaxf(expf(p_ls_s[0] + p_sw_s[0] * width + msc[MS_TOS + b]), min_sig);
    float sig_e = fmaxf(expf(p_ls_e[0] + p_sw_e[0] * width + msc[MS_TOE + b]), min_sig);
    float inv_s = 1.0f / sig_s, inv_e = 1.0f / sig_e;

    float wsv[4], wev[4], sumS = 0.f, sumE = 0.f;
    #pragma unroll
    for (int k = 0; k < 4; k++) {
        int l = tid + k * 256;
        float t = (float)l * (1.0f / 1023.0f);
        float mk = vmask[b * L_ + l];
        float ds = (t - s) * inv_s, de = (t - e) * inv_e;
        float a = expf(-0.5f * ds * ds) * mk;
        float c = expf(-0.5f * de * de) * mk;
        wsv[k] = a; wev[k] = c; sumS += a; sumE += c;
    }
    __shared__ float r0[256], r1[256];
    r0[tid] = sumS; r1[tid] = sumE; __syncthreads();
    for (int off = 128; off > 0; off >>= 1) {
        if (tid < off) { r0[tid] += r0[tid + off]; r1[tid] += r1[tid + off]; }
        __syncthreads();
    }
    float iS = 1.0f / fmaxf(r0[0], 1e-8f);
    float iE = 1.0f / fmaxf(r1[0], 1e-8f);
    unsigned short* wq = wt2 + ((size_t)b * QQ_ + q) * L_;
    unsigned short* we = wt2 + ((size_t)b * QQ_ + Q_ + q) * L_;
    #pragma unroll
    for (int k = 0; k < 4; k++) {
        int l = tid + k * 256;
        wq[l] = f2b(wsv[k] * iS);
        we[l] = f2b(wev[k] * iE);
    }
}

// ---- pool via MFMA, in-block L-split x2 -> joint bf16 [M][2048] ----
// grid (B, 16); block 512 = 8 waves: wave = (hsub 0..3, half 0..1)
__global__ __launch_bounds__(512) void k_pool_mfma(const unsigned short* __restrict__ vidT,
                                                   const unsigned short* __restrict__ wt2,
                                                   unsigned short* __restrict__ joint) {
    int b = blockIdx.x, ht = blockIdx.y;
    int wv = threadIdx.x >> 6, lane = threadIdx.x & 63;
    int hsub = wv & 3, half = wv >> 2;
    int ml = lane & 15, kg = lane >> 4;
    int hbase = ht * 64 + hsub * 16;
    const unsigned short* ap = vidT + (((size_t)b * H_ + hbase + ml) * L_ + half * 512 + kg * 8);
    const unsigned short* bp = wt2 + (((size_t)b * QQ_ + ml) * L_ + half * 512 + kg * 8);
    f4 acc[5];
    #pragma unroll
    for (int t = 0; t < 5; t++) acc[t] = (f4){0.f, 0.f, 0.f, 0.f};

    #pragma unroll 2
    for (int l0 = 0; l0 < 512; l0 += 32) {
        bf8 a = *(const bf8*)(ap + l0);
        #pragma unroll
        for (int t = 0; t < 5; t++) {
            bf8 bb = *(const bf8*)(bp + (size_t)t * 16 * L_ + l0);
            acc[t] = __builtin_amdgcn_mfma_f32_16x16x32_bf16(a, bb, acc[t], 0, 0, 0);
        }
    }

    __shared__ float cmb[4][5][64][4];          // 20 KB
    if (half == 1) {
        #pragma unroll
        for (int t = 0; t < 5; t++) {
            *(f4*)(&cmb[hsub][t][lane][0]) = acc[t];
        }
    }
    __syncthreads();
    if (half == 0) {
        #pragma unroll
        for (int t = 0; t < 5; t++) {
            f4 o = *(const f4*)(&cmb[hsub][t][lane][0]);
            acc[t] += o;
            int qq = t * 16 + ml;
            int row = b * Q_ + (qq >= Q_ ? qq - Q_ : qq);
            int col = (qq >= Q_ ? H_ : 0) + hbase + kg * 4;
            ushort4 v;
            v.x = f2b(acc[t][0]); v.y = f2b(acc[t][1]);
            v.z = f2b(acc[t][2]); v.w = f2b(acc[t][3]);
            *(ushort4*)(joint + (size_t)row * JK_ + col) = v;
        }
    }
}

// ---- MLP0 via MFMA over feat-K (2048), K-split x4, + txtpart in epilogue ----
// grid (20, 16, 4); block 256 = 4 waves; wave: 16 m x 64 n, k-range 512
__global__ __launch_bounds__(256) void k_mlp0_mfma(const unsigned short* __restrict__ joint,
                                                   const unsigned short* __restrict__ w0t,
                                                   const unsigned short* __restrict__ txtp,
                                                   unsigned short* __restrict__ part) {
    int wv = threadIdx.x >> 6, lane = threadIdx.x & 63;
    int ml = lane & 15, kg = lane >> 4;
    int mbase = blockIdx.x * 64 + wv * 16;
    int nbase = blockIdx.y * 64;
    int kbase = blockIdx.z * 512;
    const unsigned short* ap = joint + ((size_t)(mbase + ml) * JK_ + kbase + kg * 8);
    const unsigned short* bp = w0t + ((size_t)(nbase + ml) * K3_ + kbase + kg * 8);
    f4 acc[4];
    #pragma unroll
    for (int t = 0; t < 4; t++) acc[t] = (f4){0.f, 0.f, 0.f, 0.f};

    #pragma unroll 2
    for (int k0 = 0; k0 < 512; k0 += 32) {
        bf8 a = *(const bf8*)(ap + k0);
        #pragma unroll
        for (int t = 0; t < 4; t++) {
            bf8 bb = *(const bf8*)(bp + (size_t)t * 16 * K3_ + k0);
            acc[t] = __builtin_amdgcn_mfma_f32_16x16x32_bf16(a, bb, acc[t], 0, 0, 0);
        }
    }
    const unsigned short* tp = txtp + (size_t)blockIdx.z * B_ * H_;
    unsigned short* pp = part + (size_t)blockIdx.z * M_ * H_;
    #pragma unroll
    for (int t = 0; t < 4; t++) {
        int n = nbase + t * 16 + ml;
        #pragma unroll
        for (int r = 0; r < 4; r++) {
            int m = mbase + kg * 4 + r;
            int b = m / Q_;
            float v = acc[t][r] + b2f16(tp[(size_t)b * H_ + n]);
            pp[(size_t)m * H_ + n] = f2b(v);
        }
    }
}

// ---- MLP1: sum partials + bias + relu, dot w1, span update, outputs ----
__global__ void k_mlp1(const float* __restrict__ w1,
                       const float* __restrict__ b0,
                       const float* __restrict__ b1,
                       const unsigned short* __restrict__ part,
                       float* __restrict__ msc,
                       float* __restrict__ out, int pass) {
    int m = blockIdx.x, tid = threadIdx.x;
    float p0 = 0.f, p1 = 0.f;
    for (int k = tid * 2; k < H_; k += 512) {
        float h0 = b0[k], h1 = b0[k + 1];
        #pragma unroll
        for (int z = 0; z < 4; z++) {
            unsigned int u = *(const unsigned int*)(part + (size_t)z * M_ * H_ + (size_t)m * H_ + k);
            h0 += blo(u); h1 += bhi(u);
        }
        h0 = fmaxf(h0, 0.f); h1 = fmaxf(h1, 0.f);
        float2 wa = *(const float2*)(w1 + 2 * k);
        float2 wb = *(const float2*)(w1 + 2 * (k + 1));
        p0 += h0 * wa.x + h1 * wb.x;
        p1 += h0 * wa.y + h1 * wb.y;
    }
    __shared__ float r0[256], r1[256];
    r0[tid] = p0; r1[tid] = p1; __syncthreads();
    for (int off = 128; off > 0; off >>= 1) {
        if (tid < off) { r0[tid] += r0[tid + off]; r1[tid] += r1[tid + off]; }
        __syncthreads();
    }
    if (tid == 0) {
        float d0 = tanhf(r0[0] + b1[0]) * 0.1f;
        float d1 = tanhf(r1[0] + b1[1]) * 0.1f;
        float s = fminf(fmaxf(msc[MS_START + m] + d0, 0.f), 1.f);
        float e = fminf(fmaxf(msc[MS_END + m] + d1, 0.f), 1.f);
        msc[MS_START + m] = s;
        msc[MS_END + m] = e;
        float cen = 0.5f * (s + e);
        float wid = fmaxf(e - s, 1e-6f);
        out[2560 + (size_t)(pass * M_ + m) * 2 + 0] = cen;
        out[2560 + (size_t)(pass * M_ + m) * 2 + 1] = wid;
        if (pass == 1) { out[2 * m + 0] = cen; out[2 * m + 1] = wid; }
    }
}

extern "C" void kernel_launch(void* const* d_in, const int* in_sizes, int n_in,
                              void* d_out, int out_size, void* d_ws, size_t ws_size,
                              hipStream_t stream) {
    const float* spans = (const float*)d_in[0];
    const float* vid   = (const float*)d_in[1];
    const float* vmask = (const float*)d_in[2];
    const float* txt   = (const float*)d_in[3];
    const float* ls_s  = (const float*)d_in[4];
    const float* ls_e  = (const float*)d_in[5];
    const float* sw_s  = (const float*)d_in[6];
    const float* sw_e  = (const float*)d_in[7];
    const float* pw    = (const float*)d_in[8];
    const float* pb    = (const float*)d_in[9];
    const float* w0    = (const float*)d_in[10];
    const float* b0    = (const float*)d_in[11];
    const float* w1    = (const float*)d_in[12];
    const float* b1    = (const float*)d_in[13];
    char* wsb = (char*)d_ws;
    unsigned short* vidT  = (unsigned short*)(wsb + OB_VIDT);
    unsigned short* w0t   = (unsigned short*)(wsb + OB_W0T);
    unsigned short* wt2   = (unsigned short*)(wsb + OB_WT2);
    unsigned short* joint = (unsigned short*)(wsb + OB_JOINT);
    unsigned short* part  = (unsigned short*)(wsb + OB_PART);
    unsigned short* txtb  = (unsigned short*)(wsb + OB_TXTB);
    unsigned short* txtp  = (unsigned short*)(wsb + OB_TXTP);
    float* msc = (float*)(wsb + OB_MISC);
    float* out = (float*)d_out;

    hipLaunchKernelGGL(k_prologue, dim3(B_ + 5), dim3(256), 0, stream,
                       txt, pw, pb, spans, txtb, msc);
    hipLaunchKernelGGL(k_t32to16, dim3(16, 16, B_ + 3), dim3(256), 0, stream,
                       vid, vidT, w0, w0t);
    hipLaunchKernelGGL(k_txt_mlp0, dim3(16, 2, 4), dim3(256), 0, stream, txtb, w0t, txtp);
    for (int p = 0; p < 2; p++) {
        hipLaunchKernelGGL(k_weights, dim3(M_), dim3(256), 0, stream,
                           vmask, ls_s, ls_e, sw_s, sw_e, msc, wt2);
        hipLaunchKernelGGL(k_pool_mfma, dim3(B_, 16), dim3(512), 0, stream, vidT, wt2, joint);
        hipLaunchKernelGGL(k_mlp0_mfma, dim3(20, 16, 4), dim3(256), 0, stream,
                           joint, w0t, txtp, part);
        hipLaunchKernelGGL(k_mlp1, dim3(M_), dim3(256), 0, stream, w1, b0, b1, part, msc, out, p);
    }
}

// Round 6
// 440.213 us; speedup vs baseline: 4.2000x; 1.0314x over previous
//
#include <hip/hip_runtime.h>

// Problem constants
#define B_   32
#define Q_   40
#define L_   1024
#define H_   1024
#define QQ_  80
#define M_   1280          // B_*Q_
#define K3_  3072
#define JK_  2048          // joint holds only the two pooled-feature thirds

// Workspace layout (BYTE offsets)
#define OB_VIDT  0u                              // bf16 [B][H][L]    67108864
#define OB_W0T   67108864u                       // bf16 [1024][3072]  6291456
#define OB_WT2   73400320u                       // bf16 [B][80][L]    5242880
#define OB_JOINT 78643200u                       // bf16 [M][2048]     5242880
#define OB_PART  83886080u                       // bf16 [4][M][1024] 10485760
#define OB_TXTB  94371840u                       // bf16 [32][1024]      65536
#define OB_TXTP  94437376u                       // bf16 [4][32][1024]  262144
#define OB_MISC  94699520u                       // fp32 misc
// misc float offsets
#define MS_START 0
#define MS_END   1280
#define MS_TOS   2560
#define MS_TOE   2592

typedef short bf8 __attribute__((ext_vector_type(8)));   // 8 bf16 = 4 VGPRs
typedef float f4  __attribute__((ext_vector_type(4)));   // accumulator

static __device__ __forceinline__ unsigned short f2b(float f) {
    unsigned int x = __float_as_uint(f);
    unsigned int r = x + 0x7FFFu + ((x >> 16) & 1u);     // RNE
    return (unsigned short)(r >> 16);
}
static __device__ __forceinline__ float b2f16(unsigned short u) {
    return __uint_as_float((unsigned int)u << 16);
}
static __device__ __forceinline__ float blo(unsigned int u) {
    return __uint_as_float(u << 16);
}
static __device__ __forceinline__ float bhi(unsigned int u) {
    return __uint_as_float(u & 0xffff0000u);
}

// ==== launch 1: transposes (z<35) + prologue (z==35) ====
// z<32: vid [B][L][H] -> vidT [B][H][L]; z in [32,35): w0 chunk -> w0t;
// z==35: flat block id = x*16+y: <32 txt_off+txt->bf16; [32,37) span init.
__global__ __launch_bounds__(256) void k_setup(const float* __restrict__ vid,
                                               unsigned short* __restrict__ vidT,
                                               const float* __restrict__ w0,
                                               unsigned short* __restrict__ w0t,
                                               const float* __restrict__ txt,
                                               const float* __restrict__ pw,
                                               const float* __restrict__ pb,
                                               const float* __restrict__ spans,
                                               unsigned short* __restrict__ txtb,
                                               float* __restrict__ msc) {
    int z = blockIdx.z, tid = threadIdx.x;
    if (z == 35) {
        int flat = blockIdx.x * 16 + blockIdx.y;
        if (flat < B_) {
            int b = flat;
            int h4 = tid * 4;
            float4 tv = *(const float4*)(txt + (size_t)b * H_ + h4);
            float4 pa = *(const float4*)(pw + 2 * h4);
            float4 pc = *(const float4*)(pw + 2 * h4 + 4);
            float s0 = tv.x * pa.x + tv.y * pa.z + tv.z * pc.x + tv.w * pc.z;
            float s1 = tv.x * pa.y + tv.y * pa.w + tv.z * pc.y + tv.w * pc.w;
            ushort4 o;
            o.x = f2b(tv.x); o.y = f2b(tv.y); o.z = f2b(tv.z); o.w = f2b(tv.w);
            *(ushort4*)(txtb + (size_t)b * H_ + h4) = o;
            __shared__ float r0[256], r1[256];
            r0[tid] = s0; r1[tid] = s1; __syncthreads();
            for (int off = 128; off > 0; off >>= 1) {
                if (tid < off) { r0[tid] += r0[tid + off]; r1[tid] += r1[tid + off]; }
                __syncthreads();
            }
            if (tid == 0) {
                const float half_lr = 4.9999975e-07f;   // 0.5*log(1.000001)
                msc[MS_TOS + b] = tanhf(r0[0] + pb[0]) * half_lr;
                msc[MS_TOE + b] = tanhf(r1[0] + pb[1]) * half_lr;
            }
        } else if (flat < 37) {
            int i = (flat - B_) * 256 + tid;
            if (i < M_) {
                float c = spans[2 * i], w = spans[2 * i + 1];
                msc[MS_START + i] = fminf(fmaxf(c - 0.5f * w, 0.f), 1.f);
                msc[MS_END + i]   = fminf(fmaxf(c + 0.5f * w, 0.f), 1.f);
            }
        }
        return;
    }
    __shared__ float tile[64][68];
    const float* s;
    unsigned short* d;
    int dstRowStride;
    if (z < B_) {
        s = vid + (size_t)z * L_ * H_;
        d = vidT + (size_t)z * H_ * L_;
        dstRowStride = L_;
    } else {
        int zz = z - B_;
        s = w0 + (size_t)zz * 1024 * H_;
        d = w0t + (size_t)zz * 1024;
        dstRowStride = K3_;
    }
    int r0 = blockIdx.x * 64, c0 = blockIdx.y * 64;
    int col4 = (tid & 15) * 4, row = tid >> 4;
    #pragma unroll
    for (int it = 0; it < 4; it++) {
        int r = it * 16 + row;
        float4 v = *(const float4*)(s + (size_t)(r0 + r) * 1024 + c0 + col4);
        *(float4*)(&tile[r][col4]) = v;
    }
    __syncthreads();
    #pragma unroll
    for (int it = 0; it < 2; it++) {
        int slot = it * 256 + tid;
        int c = slot & 63, lo = slot >> 6;
        int r = lo * 8;
        uint4 vv;
        vv.x = (unsigned int)f2b(tile[r + 0][c]) | ((unsigned int)f2b(tile[r + 1][c]) << 16);
        vv.y = (unsigned int)f2b(tile[r + 2][c]) | ((unsigned int)f2b(tile[r + 3][c]) << 16);
        vv.z = (unsigned int)f2b(tile[r + 4][c]) | ((unsigned int)f2b(tile[r + 5][c]) << 16);
        vv.w = (unsigned int)f2b(tile[r + 6][c]) | ((unsigned int)f2b(tile[r + 7][c]) << 16);
        *(uint4*)(d + (size_t)(c0 + c) * dstRowStride + r0 + r) = vv;
    }
}

// ---- shared device body: Gaussian weights for row m given spans ----
static __device__ __forceinline__ void weights_body(int m, float s, float e,
                                                    const float* __restrict__ vmask,
                                                    float ls_s, float ls_e,
                                                    float sw_s, float sw_e,
                                                    const float* __restrict__ msc,
                                                    unsigned short* __restrict__ wt2,
                                                    float* r0, float* r1) {
    int b = m / Q_, q = m - b * Q_;
    int tid = threadIdx.x;
    float width = fmaxf(e - s, 1e-6f);
    const float min_sig = 1.0f / (4.0f * (float)L_);
    float sig_s = fmaxf(expf(ls_s + sw_s * width + msc[MS_TOS + b]), min_sig);
    float sig_e = fmaxf(expf(ls_e + sw_e * width + msc[MS_TOE + b]), min_sig);
    float inv_s = 1.0f / sig_s, inv_e = 1.0f / sig_e;

    float wsv[4], wev[4], sumS = 0.f, sumE = 0.f;
    #pragma unroll
    for (int k = 0; k < 4; k++) {
        int l = tid + k * 256;
        float t = (float)l * (1.0f / 1023.0f);
        float mk = vmask[b * L_ + l];
        float ds = (t - s) * inv_s, de = (t - e) * inv_e;
        float a = expf(-0.5f * ds * ds) * mk;
        float c = expf(-0.5f * de * de) * mk;
        wsv[k] = a; wev[k] = c; sumS += a; sumE += c;
    }
    r0[tid] = sumS; r1[tid] = sumE; __syncthreads();
    for (int off = 128; off > 0; off >>= 1) {
        if (tid < off) { r0[tid] += r0[tid + off]; r1[tid] += r1[tid + off]; }
        __syncthreads();
    }
    float iS = 1.0f / fmaxf(r0[0], 1e-8f);
    float iE = 1.0f / fmaxf(r1[0], 1e-8f);
    unsigned short* wq = wt2 + ((size_t)b * QQ_ + q) * L_;
    unsigned short* we = wt2 + ((size_t)b * QQ_ + Q_ + q) * L_;
    #pragma unroll
    for (int k = 0; k < 4; k++) {
        int l = tid + k * 256;
        wq[l] = f2b(wsv[k] * iS);
        we[l] = f2b(wev[k] * iE);
    }
}

// ==== launch 2: weights(pass0) [bid<1280] + txt_mlp0 [bid>=1280] ====
__global__ __launch_bounds__(256) void k_stage2(const float* __restrict__ vmask,
                                                const float* __restrict__ p_ls_s,
                                                const float* __restrict__ p_ls_e,
                                                const float* __restrict__ p_sw_s,
                                                const float* __restrict__ p_sw_e,
                                                const float* __restrict__ msc,
                                                unsigned short* __restrict__ wt2,
                                                const unsigned short* __restrict__ txtb,
                                                const unsigned short* __restrict__ w0t,
                                                unsigned short* __restrict__ txtp) {
    int bid = blockIdx.x;
    if (bid < M_) {
        __shared__ float r0[256], r1[256];
        int m = bid;
        weights_body(m, msc[MS_START + m], msc[MS_END + m], vmask,
                     p_ls_s[0], p_ls_e[0], p_sw_s[0], p_sw_e[0], msc, wt2, r0, r1);
        return;
    }
    int t = bid - M_;                    // 0..127
    int nIdx = t & 15, mIdx = (t >> 4) & 1, kIdx = t >> 5;
    int wv = threadIdx.x >> 6, lane = threadIdx.x & 63;
    int ml = lane & 15, kg = lane >> 4;
    int mbase = mIdx * 16;
    int nbase = nIdx * 64 + wv * 16;
    int kz = kIdx * 256;
    const unsigned short* ap = txtb + ((size_t)(mbase + ml) * H_ + kz + kg * 8);
    const unsigned short* bp = w0t + ((size_t)(nbase + ml) * K3_ + JK_ + kz + kg * 8);
    f4 acc = (f4){0.f, 0.f, 0.f, 0.f};
    #pragma unroll
    for (int k0 = 0; k0 < 256; k0 += 32) {
        bf8 a = *(const bf8*)(ap + k0);
        bf8 bb = *(const bf8*)(bp + k0);
        acc = __builtin_amdgcn_mfma_f32_16x16x32_bf16(a, bb, acc, 0, 0, 0);
    }
    unsigned short* pp = txtp + (size_t)kIdx * B_ * H_;
    int n = nbase + ml;
    #pragma unroll
    for (int r = 0; r < 4; r++) {
        int m = mbase + kg * 4 + r;
        pp[(size_t)m * H_ + n] = f2b(acc[r]);
    }
}

// ==== pool via MFMA, in-block L-split x2 -> joint bf16 [M][2048] ====
// grid (B, 16); block 512 = 8 waves: wave = (hsub 0..3, half 0..1)
__global__ __launch_bounds__(512) void k_pool_mfma(const unsigned short* __restrict__ vidT,
                                                   const unsigned short* __restrict__ wt2,
                                                   unsigned short* __restrict__ joint) {
    int b = blockIdx.x, ht = blockIdx.y;
    int wv = threadIdx.x >> 6, lane = threadIdx.x & 63;
    int hsub = wv & 3, half = wv >> 2;
    int ml = lane & 15, kg = lane >> 4;
    int hbase = ht * 64 + hsub * 16;
    const unsigned short* ap = vidT + (((size_t)b * H_ + hbase + ml) * L_ + half * 512 + kg * 8);
    const unsigned short* bp = wt2 + (((size_t)b * QQ_ + ml) * L_ + half * 512 + kg * 8);
    f4 acc[5];
    #pragma unroll
    for (int t = 0; t < 5; t++) acc[t] = (f4){0.f, 0.f, 0.f, 0.f};

    #pragma unroll 4
    for (int l0 = 0; l0 < 512; l0 += 32) {
        bf8 a = *(const bf8*)(ap + l0);
        #pragma unroll
        for (int t = 0; t < 5; t++) {
            bf8 bb = *(const bf8*)(bp + (size_t)t * 16 * L_ + l0);
            acc[t] = __builtin_amdgcn_mfma_f32_16x16x32_bf16(a, bb, acc[t], 0, 0, 0);
        }
    }

    __shared__ float cmb[4][5][64][4];          // 20 KB
    if (half == 1) {
        #pragma unroll
        for (int t = 0; t < 5; t++) {
            *(f4*)(&cmb[hsub][t][lane][0]) = acc[t];
        }
    }
    __syncthreads();
    if (half == 0) {
        #pragma unroll
        for (int t = 0; t < 5; t++) {
            f4 o = *(const f4*)(&cmb[hsub][t][lane][0]);
            acc[t] += o;
            int qq = t * 16 + ml;
            int row = b * Q_ + (qq >= Q_ ? qq - Q_ : qq);
            int col = (qq >= Q_ ? H_ : 0) + hbase + kg * 4;
            ushort4 v;
            v.x = f2b(acc[t][0]); v.y = f2b(acc[t][1]);
            v.z = f2b(acc[t][2]); v.w = f2b(acc[t][3]);
            *(ushort4*)(joint + (size_t)row * JK_ + col) = v;
        }
    }
}

// ==== MLP0 via MFMA over feat-K (2048), K-split x4, + txtpart in epilogue ====
// grid (20, 16, 4); block 256 = 4 waves; wave: 16 m x 64 n, k-range 512
__global__ __launch_bounds__(256) void k_mlp0_mfma(const unsigned short* __restrict__ joint,
                                                   const unsigned short* __restrict__ w0t,
                                                   const unsigned short* __restrict__ txtp,
                                                   unsigned short* __restrict__ part) {
    int wv = threadIdx.x >> 6, lane = threadIdx.x & 63;
    int ml = lane & 15, kg = lane >> 4;
    int mbase = blockIdx.x * 64 + wv * 16;
    int nbase = blockIdx.y * 64;
    int kbase = blockIdx.z * 512;
    const unsigned short* ap = joint + ((size_t)(mbase + ml) * JK_ + kbase + kg * 8);
    const unsigned short* bp = w0t + ((size_t)(nbase + ml) * K3_ + kbase + kg * 8);
    f4 acc[4];
    #pragma unroll
    for (int t = 0; t < 4; t++) acc[t] = (f4){0.f, 0.f, 0.f, 0.f};

    #pragma unroll 4
    for (int k0 = 0; k0 < 512; k0 += 32) {
        bf8 a = *(const bf8*)(ap + k0);
        #pragma unroll
        for (int t = 0; t < 4; t++) {
            bf8 bb = *(const bf8*)(bp + (size_t)t * 16 * K3_ + k0);
            acc[t] = __builtin_amdgcn_mfma_f32_16x16x32_bf16(a, bb, acc[t], 0, 0, 0);
        }
    }
    const unsigned short* tp = txtp + (size_t)blockIdx.z * B_ * H_;
    unsigned short* pp = part + (size_t)blockIdx.z * M_ * H_;
    #pragma unroll
    for (int t = 0; t < 4; t++) {
        int n = nbase + t * 16 + ml;
        #pragma unroll
        for (int r = 0; r < 4; r++) {
            int m = mbase + kg * 4 + r;
            int b = m / Q_;
            float v = acc[t][r] + b2f16(tp[(size_t)b * H_ + n]);
            pp[(size_t)m * H_ + n] = f2b(v);
        }
    }
}

// ==== MLP1 + span update + outputs (+ weights for NEXT pass if do_weights) ====
__global__ __launch_bounds__(256) void k_mlp1w(const float* __restrict__ w1,
                                               const float* __restrict__ b0,
                                               const float* __restrict__ b1,
                                               const unsigned short* __restrict__ part,
                                               float* __restrict__ msc,
                                               float* __restrict__ out, int pass,
                                               int do_weights,
                                               const float* __restrict__ vmask,
                                               const float* __restrict__ p_ls_s,
                                               const float* __restrict__ p_ls_e,
                                               const float* __restrict__ p_sw_s,
                                               const float* __restrict__ p_sw_e,
                                               unsigned short* __restrict__ wt2) {
    int m = blockIdx.x, tid = threadIdx.x;
    int k4 = tid * 4;
    float4 bb = *(const float4*)(b0 + k4);
    float h0 = bb.x, h1 = bb.y, h2 = bb.z, h3 = bb.w;
    #pragma unroll
    for (int z = 0; z < 4; z++) {
        uint2 u = *(const uint2*)(part + (size_t)z * M_ * H_ + (size_t)m * H_ + k4);
        h0 += blo(u.x); h1 += bhi(u.x);
        h2 += blo(u.y); h3 += bhi(u.y);
    }
    h0 = fmaxf(h0, 0.f); h1 = fmaxf(h1, 0.f);
    h2 = fmaxf(h2, 0.f); h3 = fmaxf(h3, 0.f);
    float4 wa = *(const float4*)(w1 + 2 * k4);
    float4 wb = *(const float4*)(w1 + 2 * k4 + 4);
    float p0 = h0 * wa.x + h1 * wa.z + h2 * wb.x + h3 * wb.z;
    float p1 = h0 * wa.y + h1 * wa.w + h2 * wb.y + h3 * wb.w;

    __shared__ float r0[256], r1[256];
    __shared__ float sh_s, sh_e;
    r0[tid] = p0; r1[tid] = p1; __syncthreads();
    for (int off = 128; off > 0; off >>= 1) {
        if (tid < off) { r0[tid] += r0[tid + off]; r1[tid] += r1[tid + off]; }
        __syncthreads();
    }
    if (tid == 0) {
        float d0 = tanhf(r0[0] + b1[0]) * 0.1f;
        float d1 = tanhf(r1[0] + b1[1]) * 0.1f;
        float s = fminf(fmaxf(msc[MS_START + m] + d0, 0.f), 1.f);
        float e = fminf(fmaxf(msc[MS_END + m] + d1, 0.f), 1.f);
        msc[MS_START + m] = s;
        msc[MS_END + m] = e;
        sh_s = s; sh_e = e;
        float cen = 0.5f * (s + e);
        float wid = fmaxf(e - s, 1e-6f);
        out[2560 + (size_t)(pass * M_ + m) * 2 + 0] = cen;
        out[2560 + (size_t)(pass * M_ + m) * 2 + 1] = wid;
        if (pass == 1) { out[2 * m + 0] = cen; out[2 * m + 1] = wid; }
    }
    __syncthreads();
    if (do_weights) {
        weights_body(m, sh_s, sh_e, vmask,
                     p_ls_s[0], p_ls_e[0], p_sw_s[0], p_sw_e[0], msc, wt2, r0, r1);
    }
}

extern "C" void kernel_launch(void* const* d_in, const int* in_sizes, int n_in,
                              void* d_out, int out_size, void* d_ws, size_t ws_size,
                              hipStream_t stream) {
    const float* spans = (const float*)d_in[0];
    const float* vid   = (const float*)d_in[1];
    const float* vmask = (const float*)d_in[2];
    const float* txt   = (const float*)d_in[3];
    const float* ls_s  = (const float*)d_in[4];
    const float* ls_e  = (const float*)d_in[5];
    const float* sw_s  = (const float*)d_in[6];
    const float* sw_e  = (const float*)d_in[7];
    const float* pw    = (const float*)d_in[8];
    const float* pb    = (const float*)d_in[9];
    const float* w0    = (const float*)d_in[10];
    const float* b0    = (const float*)d_in[11];
    const float* w1    = (const float*)d_in[12];
    const float* b1    = (const float*)d_in[13];
    char* wsb = (char*)d_ws;
    unsigned short* vidT  = (unsigned short*)(wsb + OB_VIDT);
    unsigned short* w0t   = (unsigned short*)(wsb + OB_W0T);
    unsigned short* wt2   = (unsigned short*)(wsb + OB_WT2);
    unsigned short* joint = (unsigned short*)(wsb + OB_JOINT);
    unsigned short* part  = (unsigned short*)(wsb + OB_PART);
    unsigned short* txtb  = (unsigned short*)(wsb + OB_TXTB);
    unsigned short* txtp  = (unsigned short*)(wsb + OB_TXTP);
    float* msc = (float*)(wsb + OB_MISC);
    float* out = (float*)d_out;

    hipLaunchKernelGGL(k_setup, dim3(16, 16, 36), dim3(256), 0, stream,
                       vid, vidT, w0, w0t, txt, pw, pb, spans, txtb, msc);
    hipLaunchKernelGGL(k_stage2, dim3(M_ + 128), dim3(256), 0, stream,
                       vmask, ls_s, ls_e, sw_s, sw_e, msc, wt2, txtb, w0t, txtp);
    for (int p = 0; p < 2; p++) {
        hipLaunchKernelGGL(k_pool_mfma, dim3(B_, 16), dim3(512), 0, stream, vidT, wt2, joint);
        hipLaunchKernelGGL(k_mlp0_mfma, dim3(20, 16, 4), dim3(256), 0, stream,
                           joint, w0t, txtp, part);
        hipLaunchKernelGGL(k_mlp1w, dim3(M_), dim3(256), 0, stream,
                           w1, b0, b1, part, msc, out, p, (p == 0) ? 1 : 0,
                           vmask, ls_s, ls_e, sw_s, sw_e, wt2);
    }
}

// Round 7
// 435.523 us; speedup vs baseline: 4.2453x; 1.0108x over previous
//
#include <hip/hip_runtime.h>

// Problem constants
#define B_   32
#define Q_   40
#define L_   1024
#define H_   1024
#define QQ_  80
#define M_   1280          // B_*Q_
#define K3_  3072
#define JK_  2048          // joint holds only the two pooled-feature thirds

// Workspace layout (BYTE offsets)
#define OB_VIDT  0u                              // bf16 [B][H][L]    67108864
#define OB_W0T   67108864u                       // bf16 [1024][3072]  6291456
#define OB_WT2   73400320u                       // bf16 [B][80][L]    5242880
#define OB_JOINT 78643200u                       // bf16 [M][2048]     5242880
#define OB_PART  83886080u                       // bf16 [4][M][1024] 10485760
#define OB_TXTB  94371840u                       // bf16 [32][1024]      65536
#define OB_TXTP  94437376u                       // bf16 [4][32][1024]  262144
#define OB_MISC  94699520u                       // fp32 misc
// misc float offsets
#define MS_START 0
#define MS_END   1280
#define MS_TOS   2560
#define MS_TOE   2592

typedef short bf8 __attribute__((ext_vector_type(8)));   // 8 bf16 = 4 VGPRs
typedef float f4  __attribute__((ext_vector_type(4)));   // accumulator

static __device__ __forceinline__ unsigned short f2b(float f) {
    unsigned int x = __float_as_uint(f);
    unsigned int r = x + 0x7FFFu + ((x >> 16) & 1u);     // RNE
    return (unsigned short)(r >> 16);
}
static __device__ __forceinline__ float b2f16(unsigned short u) {
    return __uint_as_float((unsigned int)u << 16);
}
static __device__ __forceinline__ float blo(unsigned int u) {
    return __uint_as_float(u << 16);
}
static __device__ __forceinline__ float bhi(unsigned int u) {
    return __uint_as_float(u & 0xffff0000u);
}

// ==== launch 1: transposes (z<35) + prologue (z==35) ====
// z<32: vid [B][L][H] -> vidT [B][H][L]; z in [32,35): w0 chunk -> w0t;
// z==35: flat block id = x*16+y: <32 txt_off+txt->bf16; [32,37) span init.
__global__ __launch_bounds__(256) void k_setup(const float* __restrict__ vid,
                                               unsigned short* __restrict__ vidT,
                                               const float* __restrict__ w0,
                                               unsigned short* __restrict__ w0t,
                                               const float* __restrict__ txt,
                                               const float* __restrict__ pw,
                                               const float* __restrict__ pb,
                                               const float* __restrict__ spans,
                                               unsigned short* __restrict__ txtb,
                                               float* __restrict__ msc) {
    int z = blockIdx.z, tid = threadIdx.x;
    if (z == 35) {
        int flat = blockIdx.x * 16 + blockIdx.y;
        if (flat < B_) {
            int b = flat;
            int h4 = tid * 4;
            float4 tv = *(const float4*)(txt + (size_t)b * H_ + h4);
            float4 pa = *(const float4*)(pw + 2 * h4);
            float4 pc = *(const float4*)(pw + 2 * h4 + 4);
            float s0 = tv.x * pa.x + tv.y * pa.z + tv.z * pc.x + tv.w * pc.z;
            float s1 = tv.x * pa.y + tv.y * pa.w + tv.z * pc.y + tv.w * pc.w;
            ushort4 o;
            o.x = f2b(tv.x); o.y = f2b(tv.y); o.z = f2b(tv.z); o.w = f2b(tv.w);
            *(ushort4*)(txtb + (size_t)b * H_ + h4) = o;
            __shared__ float r0[256], r1[256];
            r0[tid] = s0; r1[tid] = s1; __syncthreads();
            for (int off = 128; off > 0; off >>= 1) {
                if (tid < off) { r0[tid] += r0[tid + off]; r1[tid] += r1[tid + off]; }
                __syncthreads();
            }
            if (tid == 0) {
                const float half_lr = 4.9999975e-07f;   // 0.5*log(1.000001)
                msc[MS_TOS + b] = tanhf(r0[0] + pb[0]) * half_lr;
                msc[MS_TOE + b] = tanhf(r1[0] + pb[1]) * half_lr;
            }
        } else if (flat < 37) {
            int i = (flat - B_) * 256 + tid;
            if (i < M_) {
                float c = spans[2 * i], w = spans[2 * i + 1];
                msc[MS_START + i] = fminf(fmaxf(c - 0.5f * w, 0.f), 1.f);
                msc[MS_END + i]   = fminf(fmaxf(c + 0.5f * w, 0.f), 1.f);
            }
        }
        return;
    }
    // transpose tile: pad row to 69 floats -> transposed-read bank pattern 2-way (free)
    __shared__ float tile[64][69];
    const float* s;
    unsigned short* d;
    int dstRowStride;
    if (z < B_) {
        s = vid + (size_t)z * L_ * H_;
        d = vidT + (size_t)z * H_ * L_;
        dstRowStride = L_;
    } else {
        int zz = z - B_;
        s = w0 + (size_t)zz * 1024 * H_;
        d = w0t + (size_t)zz * 1024;
        dstRowStride = K3_;
    }
    int r0 = blockIdx.x * 64, c0 = blockIdx.y * 64;
    int col4 = (tid & 15) * 4, row = tid >> 4;
    #pragma unroll
    for (int it = 0; it < 4; it++) {
        int r = it * 16 + row;
        float4 v = *(const float4*)(s + (size_t)(r0 + r) * 1024 + c0 + col4);
        *(float4*)(&tile[r][col4]) = v;
    }
    __syncthreads();
    // write stage: slot = c*8 + chunk; 8 consecutive lanes write the 8
    // consecutive 16B chunks of dst row (c0+c) -> 128B-contiguous per 8 lanes
    #pragma unroll
    for (int it = 0; it < 2; it++) {
        int slot = it * 256 + tid;
        int c = slot >> 3, chunk = slot & 7;
        int r = chunk * 8;
        uint4 vv;
        vv.x = (unsigned int)f2b(tile[r + 0][c]) | ((unsigned int)f2b(tile[r + 1][c]) << 16);
        vv.y = (unsigned int)f2b(tile[r + 2][c]) | ((unsigned int)f2b(tile[r + 3][c]) << 16);
        vv.z = (unsigned int)f2b(tile[r + 4][c]) | ((unsigned int)f2b(tile[r + 5][c]) << 16);
        vv.w = (unsigned int)f2b(tile[r + 6][c]) | ((unsigned int)f2b(tile[r + 7][c]) << 16);
        *(uint4*)(d + (size_t)(c0 + c) * dstRowStride + r0 + r) = vv;
    }
}

// ---- shared device body: Gaussian weights for row m given spans ----
static __device__ __forceinline__ void weights_body(int m, float s, float e,
                                                    const float* __restrict__ vmask,
                                                    float ls_s, float ls_e,
                                                    float sw_s, float sw_e,
                                                    const float* __restrict__ msc,
                                                    unsigned short* __restrict__ wt2,
                                                    float* r0, float* r1) {
    int b = m / Q_, q = m - b * Q_;
    int tid = threadIdx.x;
    float width = fmaxf(e - s, 1e-6f);
    const float min_sig = 1.0f / (4.0f * (float)L_);
    float sig_s = fmaxf(expf(ls_s + sw_s * width + msc[MS_TOS + b]), min_sig);
    float sig_e = fmaxf(expf(ls_e + sw_e * width + msc[MS_TOE + b]), min_sig);
    float inv_s = 1.0f / sig_s, inv_e = 1.0f / sig_e;

    float wsv[4], wev[4], sumS = 0.f, sumE = 0.f;
    #pragma unroll
    for (int k = 0; k < 4; k++) {
        int l = tid + k * 256;
        float t = (float)l * (1.0f / 1023.0f);
        float mk = vmask[b * L_ + l];
        float ds = (t - s) * inv_s, de = (t - e) * inv_e;
        float a = expf(-0.5f * ds * ds) * mk;
        float c = expf(-0.5f * de * de) * mk;
        wsv[k] = a; wev[k] = c; sumS += a; sumE += c;
    }
    r0[tid] = sumS; r1[tid] = sumE; __syncthreads();
    for (int off = 128; off > 0; off >>= 1) {
        if (tid < off) { r0[tid] += r0[tid + off]; r1[tid] += r1[tid + off]; }
        __syncthreads();
    }
    float iS = 1.0f / fmaxf(r0[0], 1e-8f);
    float iE = 1.0f / fmaxf(r1[0], 1e-8f);
    unsigned short* wq = wt2 + ((size_t)b * QQ_ + q) * L_;
    unsigned short* we = wt2 + ((size_t)b * QQ_ + Q_ + q) * L_;
    #pragma unroll
    for (int k = 0; k < 4; k++) {
        int l = tid + k * 256;
        wq[l] = f2b(wsv[k] * iS);
        we[l] = f2b(wev[k] * iE);
    }
}

// ==== launch 2: weights(pass0) [bid<1280] + txt_mlp0 [bid>=1280] ====
__global__ __launch_bounds__(256) void k_stage2(const float* __restrict__ vmask,
                                                const float* __restrict__ p_ls_s,
                                                const float* __restrict__ p_ls_e,
                                                const float* __restrict__ p_sw_s,
                                                const float* __restrict__ p_sw_e,
                                                const float* __restrict__ msc,
                                                unsigned short* __restrict__ wt2,
                                                const unsigned short* __restrict__ txtb,
                                                const unsigned short* __restrict__ w0t,
                                                unsigned short* __restrict__ txtp) {
    int bid = blockIdx.x;
    if (bid < M_) {
        __shared__ float r0[256], r1[256];
        int m = bid;
        weights_body(m, msc[MS_START + m], msc[MS_END + m], vmask,
                     p_ls_s[0], p_ls_e[0], p_sw_s[0], p_sw_e[0], msc, wt2, r0, r1);
        return;
    }
    int t = bid - M_;                    // 0..127
    int nIdx = t & 15, mIdx = (t >> 4) & 1, kIdx = t >> 5;
    int wv = threadIdx.x >> 6, lane = threadIdx.x & 63;
    int ml = lane & 15, kg = lane >> 4;
    int mbase = mIdx * 16;
    int nbase = nIdx * 64 + wv * 16;
    int kz = kIdx * 256;
    const unsigned short* ap = txtb + ((size_t)(mbase + ml) * H_ + kz + kg * 8);
    const unsigned short* bp = w0t + ((size_t)(nbase + ml) * K3_ + JK_ + kz + kg * 8);
    f4 acc = (f4){0.f, 0.f, 0.f, 0.f};
    #pragma unroll
    for (int k0 = 0; k0 < 256; k0 += 32) {
        bf8 a = *(const bf8*)(ap + k0);
        bf8 bb = *(const bf8*)(bp + k0);
        acc = __builtin_amdgcn_mfma_f32_16x16x32_bf16(a, bb, acc, 0, 0, 0);
    }
    unsigned short* pp = txtp + (size_t)kIdx * B_ * H_;
    int n = nbase + ml;
    #pragma unroll
    for (int r = 0; r < 4; r++) {
        int m = mbase + kg * 4 + r;
        pp[(size_t)m * H_ + n] = f2b(acc[r]);
    }
}

// ==== pool via MFMA, in-block L-split x2 -> joint bf16 [M][2048] ====
// grid (B, 16); block 512 = 8 waves: wave = (hsub 0..3, half 0..1)
__global__ __launch_bounds__(512) void k_pool_mfma(const unsigned short* __restrict__ vidT,
                                                   const unsigned short* __restrict__ wt2,
                                                   unsigned short* __restrict__ joint) {
    int b = blockIdx.x, ht = blockIdx.y;
    int wv = threadIdx.x >> 6, lane = threadIdx.x & 63;
    int hsub = wv & 3, half = wv >> 2;
    int ml = lane & 15, kg = lane >> 4;
    int hbase = ht * 64 + hsub * 16;
    const unsigned short* ap = vidT + (((size_t)b * H_ + hbase + ml) * L_ + half * 512 + kg * 8);
    const unsigned short* bp = wt2 + (((size_t)b * QQ_ + ml) * L_ + half * 512 + kg * 8);
    f4 acc[5];
    #pragma unroll
    for (int t = 0; t < 5; t++) acc[t] = (f4){0.f, 0.f, 0.f, 0.f};

    #pragma unroll 4
    for (int l0 = 0; l0 < 512; l0 += 32) {
        bf8 a = *(const bf8*)(ap + l0);
        #pragma unroll
        for (int t = 0; t < 5; t++) {
            bf8 bb = *(const bf8*)(bp + (size_t)t * 16 * L_ + l0);
            acc[t] = __builtin_amdgcn_mfma_f32_16x16x32_bf16(a, bb, acc[t], 0, 0, 0);
        }
    }

    __shared__ float cmb[4][5][64][4];          // 20 KB
    if (half == 1) {
        #pragma unroll
        for (int t = 0; t < 5; t++) {
            *(f4*)(&cmb[hsub][t][lane][0]) = acc[t];
        }
    }
    __syncthreads();
    if (half == 0) {
        #pragma unroll
        for (int t = 0; t < 5; t++) {
            f4 o = *(const f4*)(&cmb[hsub][t][lane][0]);
            acc[t] += o;
            int qq = t * 16 + ml;
            int row = b * Q_ + (qq >= Q_ ? qq - Q_ : qq);
            int col = (qq >= Q_ ? H_ : 0) + hbase + kg * 4;
            ushort4 v;
            v.x = f2b(acc[t][0]); v.y = f2b(acc[t][1]);
            v.z = f2b(acc[t][2]); v.w = f2b(acc[t][3]);
            *(ushort4*)(joint + (size_t)row * JK_ + col) = v;
        }
    }
}

// ==== MLP0 via MFMA over feat-K (2048), K-split x4, + txtpart in epilogue ====
// grid (20, 16, 4); block 256 = 4 waves; wave: 16 m x 64 n, k-range 512
__global__ __launch_bounds__(256) void k_mlp0_mfma(const unsigned short* __restrict__ joint,
                                                   const unsigned short* __restrict__ w0t,
                                                   const unsigned short* __restrict__ txtp,
                                                   unsigned short* __restrict__ part) {
    int wv = threadIdx.x >> 6, lane = threadIdx.x & 63;
    int ml = lane & 15, kg = lane >> 4;
    int mbase = blockIdx.x * 64 + wv * 16;
    int nbase = blockIdx.y * 64;
    int kbase = blockIdx.z * 512;
    const unsigned short* ap = joint + ((size_t)(mbase + ml) * JK_ + kbase + kg * 8);
    const unsigned short* bp = w0t + ((size_t)(nbase + ml) * K3_ + kbase + kg * 8);
    f4 acc[4];
    #pragma unroll
    for (int t = 0; t < 4; t++) acc[t] = (f4){0.f, 0.f, 0.f, 0.f};

    #pragma unroll 4
    for (int k0 = 0; k0 < 512; k0 += 32) {
        bf8 a = *(const bf8*)(ap + k0);
        #pragma unroll
        for (int t = 0; t < 4; t++) {
            bf8 bb = *(const bf8*)(bp + (size_t)t * 16 * K3_ + k0);
            acc[t] = __builtin_amdgcn_mfma_f32_16x16x32_bf16(a, bb, acc[t], 0, 0, 0);
        }
    }
    const unsigned short* tp = txtp + (size_t)blockIdx.z * B_ * H_;
    unsigned short* pp = part + (size_t)blockIdx.z * M_ * H_;
    #pragma unroll
    for (int t = 0; t < 4; t++) {
        int n = nbase + t * 16 + ml;
        #pragma unroll
        for (int r = 0; r < 4; r++) {
            int m = mbase + kg * 4 + r;
            int b = m / Q_;
            float v = acc[t][r] + b2f16(tp[(size_t)b * H_ + n]);
            pp[(size_t)m * H_ + n] = f2b(v);
        }
    }
}

// ==== MLP1 + span update + outputs (+ weights for NEXT pass if do_weights) ====
__global__ __launch_bounds__(256) void k_mlp1w(const float* __restrict__ w1,
                                               const float* __restrict__ b0,
                                               const float* __restrict__ b1,
                                               const unsigned short* __restrict__ part,
                                               float* __restrict__ msc,
                                               float* __restrict__ out, int pass,
                                               int do_weights,
                                               const float* __restrict__ vmask,
                                               const float* __restrict__ p_ls_s,
                                               const float* __restrict__ p_ls_e,
                                               const float* __restrict__ p_sw_s,
                                               const float* __restrict__ p_sw_e,
                                               unsigned short* __restrict__ wt2) {
    int m = blockIdx.x, tid = threadIdx.x;
    int k4 = tid * 4;
    float4 bb = *(const float4*)(b0 + k4);
    float h0 = bb.x, h1 = bb.y, h2 = bb.z, h3 = bb.w;
    #pragma unroll
    for (int z = 0; z < 4; z++) {
        uint2 u = *(const uint2*)(part + (size_t)z * M_ * H_ + (size_t)m * H_ + k4);
        h0 += blo(u.x); h1 += bhi(u.x);
        h2 += blo(u.y); h3 += bhi(u.y);
    }
    h0 = fmaxf(h0, 0.f); h1 = fmaxf(h1, 0.f);
    h2 = fmaxf(h2, 0.f); h3 = fmaxf(h3, 0.f);
    float4 wa = *(const float4*)(w1 + 2 * k4);
    float4 wb = *(const float4*)(w1 + 2 * k4 + 4);
    float p0 = h0 * wa.x + h1 * wa.z + h2 * wb.x + h3 * wb.z;
    float p1 = h0 * wa.y + h1 * wa.w + h2 * wb.y + h3 * wb.w;

    __shared__ float r0[256], r1[256];
    __shared__ float sh_s, sh_e;
    r0[tid] = p0; r1[tid] = p1; __syncthreads();
    for (int off = 128; off > 0; off >>= 1) {
        if (tid < off) { r0[tid] += r0[tid + off]; r1[tid] += r1[tid + off]; }
        __syncthreads();
    }
    if (tid == 0) {
        float d0 = tanhf(r0[0] + b1[0]) * 0.1f;
        float d1 = tanhf(r1[0] + b1[1]) * 0.1f;
        float s = fminf(fmaxf(msc[MS_START + m] + d0, 0.f), 1.f);
        float e = fminf(fmaxf(msc[MS_END + m] + d1, 0.f), 1.f);
        msc[MS_START + m] = s;
        msc[MS_END + m] = e;
        sh_s = s; sh_e = e;
        float cen = 0.5f * (s + e);
        float wid = fmaxf(e - s, 1e-6f);
        out[2560 + (size_t)(pass * M_ + m) * 2 + 0] = cen;
        out[2560 + (size_t)(pass * M_ + m) * 2 + 1] = wid;
        if (pass == 1) { out[2 * m + 0] = cen; out[2 * m + 1] = wid; }
    }
    __syncthreads();
    if (do_weights) {
        weights_body(m, sh_s, sh_e, vmask,
                     p_ls_s[0], p_ls_e[0], p_sw_s[0], p_sw_e[0], msc, wt2, r0, r1);
    }
}

extern "C" void kernel_launch(void* const* d_in, const int* in_sizes, int n_in,
                              void* d_out, int out_size, void* d_ws, size_t ws_size,
                              hipStream_t stream) {
    const float* spans = (const float*)d_in[0];
    const float* vid   = (const float*)d_in[1];
    const float* vmask = (const float*)d_in[2];
    const float* txt   = (const float*)d_in[3];
    const float* ls_s  = (const float*)d_in[4];
    const float* ls_e  = (const float*)d_in[5];
    const float* sw_s  = (const float*)d_in[6];
    const float* sw_e  = (const float*)d_in[7];
    const float* pw    = (const float*)d_in[8];
    const float* pb    = (const float*)d_in[9];
    const float* w0    = (const float*)d_in[10];
    const float* b0    = (const float*)d_in[11];
    const float* w1    = (const float*)d_in[12];
    const float* b1    = (const float*)d_in[13];
    char* wsb = (char*)d_ws;
    unsigned short* vidT  = (unsigned short*)(wsb + OB_VIDT);
    unsigned short* w0t   = (unsigned short*)(wsb + OB_W0T);
    unsigned short* wt2   = (unsigned short*)(wsb + OB_WT2);
    unsigned short* joint = (unsigned short*)(wsb + OB_JOINT);
    unsigned short* part  = (unsigned short*)(wsb + OB_PART);
    unsigned short* txtb  = (unsigned short*)(wsb + OB_TXTB);
    unsigned short* txtp  = (unsigned short*)(wsb + OB_TXTP);
    float* msc = (float*)(wsb + OB_MISC);
    float* out = (float*)d_out;

    hipLaunchKernelGGL(k_setup, dim3(16, 16, 36), dim3(256), 0, stream,
                       vid, vidT, w0, w0t, txt, pw, pb, spans, txtb, msc);
    hipLaunchKernelGGL(k_stage2, dim3(M_ + 128), dim3(256), 0, stream,
                       vmask, ls_s, ls_e, sw_s, sw_e, msc, wt2, txtb, w0t, txtp);
    for (int p = 0; p < 2; p++) {
        hipLaunchKernelGGL(k_pool_mfma, dim3(B_, 16), dim3(512), 0, stream, vidT, wt2, joint);
        hipLaunchKernelGGL(k_mlp0_mfma, dim3(20, 16, 4), dim3(256), 0, stream,
                           joint, w0t, txtp, part);
        hipLaunchKernelGGL(k_mlp1w, dim3(M_), dim3(256), 0, stream,
                           w1, b0, b1, part, msc, out, p, (p == 0) ? 1 : 0,
                           vmask, ls_s, ls_e, sw_s, sw_e, wt2);
    }
}

// Round 8
// 396.907 us; speedup vs baseline: 4.6583x; 1.0973x over previous
//
#include <hip/hip_runtime.h>

// Problem constants
#define B_   32
#define Q_   40
#define L_   1024
#define H_   1024
#define QQ_  80
#define M_   1280          // B_*Q_
#define K3_  3072
#define JK_  2048          // joint holds only the two pooled-feature thirds

// Workspace layout (BYTE offsets) — vidT eliminated this round
#define OB_W0T   0u                              // bf16 [1024][3072]  6291456
#define OB_WT2   6291456u                        // bf16 [B][80][L]    5242880
#define OB_JOINT 11534336u                       // bf16 [M][2048]     5242880
#define OB_PART  16777216u                       // bf16 [4][M][1024] 10485760
#define OB_TXTB  27262976u                       // bf16 [32][1024]      65536
#define OB_TXTP  27328512u                       // bf16 [4][32][1024]  262144
#define OB_MISC  27590656u                       // fp32 misc
// misc float offsets
#define MS_START 0
#define MS_END   1280
#define MS_TOS   2560
#define MS_TOE   2592

typedef short bf8 __attribute__((ext_vector_type(8)));   // 8 bf16 = 4 VGPRs
typedef float f4  __attribute__((ext_vector_type(4)));   // accumulator

static __device__ __forceinline__ unsigned short f2b(float f) {
    unsigned int x = __float_as_uint(f);
    unsigned int r = x + 0x7FFFu + ((x >> 16) & 1u);     // RNE
    return (unsigned short)(r >> 16);
}
static __device__ __forceinline__ float b2f16(unsigned short u) {
    return __uint_as_float((unsigned int)u << 16);
}
static __device__ __forceinline__ float blo(unsigned int u) {
    return __uint_as_float(u << 16);
}
static __device__ __forceinline__ float bhi(unsigned int u) {
    return __uint_as_float(u & 0xffff0000u);
}

// ==== launch 1: w0 transpose (z<3) + prologue (z==3) ====
__global__ __launch_bounds__(256) void k_setup(const float* __restrict__ w0,
                                               unsigned short* __restrict__ w0t,
                                               const float* __restrict__ txt,
                                               const float* __restrict__ pw,
                                               const float* __restrict__ pb,
                                               const float* __restrict__ spans,
                                               unsigned short* __restrict__ txtb,
                                               float* __restrict__ msc) {
    int z = blockIdx.z, tid = threadIdx.x;
    if (z == 3) {
        int flat = blockIdx.x * 16 + blockIdx.y;
        if (flat < B_) {
            int b = flat;
            int h4 = tid * 4;
            float4 tv = *(const float4*)(txt + (size_t)b * H_ + h4);
            float4 pa = *(const float4*)(pw + 2 * h4);
            float4 pc = *(const float4*)(pw + 2 * h4 + 4);
            float s0 = tv.x * pa.x + tv.y * pa.z + tv.z * pc.x + tv.w * pc.z;
            float s1 = tv.x * pa.y + tv.y * pa.w + tv.z * pc.y + tv.w * pc.w;
            ushort4 o;
            o.x = f2b(tv.x); o.y = f2b(tv.y); o.z = f2b(tv.z); o.w = f2b(tv.w);
            *(ushort4*)(txtb + (size_t)b * H_ + h4) = o;
            __shared__ float r0[256], r1[256];
            r0[tid] = s0; r1[tid] = s1; __syncthreads();
            for (int off = 128; off > 0; off >>= 1) {
                if (tid < off) { r0[tid] += r0[tid + off]; r1[tid] += r1[tid + off]; }
                __syncthreads();
            }
            if (tid == 0) {
                const float half_lr = 4.9999975e-07f;   // 0.5*log(1.000001)
                msc[MS_TOS + b] = tanhf(r0[0] + pb[0]) * half_lr;
                msc[MS_TOE + b] = tanhf(r1[0] + pb[1]) * half_lr;
            }
        } else if (flat < 37) {
            int i = (flat - B_) * 256 + tid;
            if (i < M_) {
                float c = spans[2 * i], w = spans[2 * i + 1];
                msc[MS_START + i] = fminf(fmaxf(c - 0.5f * w, 0.f), 1.f);
                msc[MS_END + i]   = fminf(fmaxf(c + 0.5f * w, 0.f), 1.f);
            }
        }
        return;
    }
    // w0 [3072][1024] -> w0t [1024][3072], chunk z covers rows z*1024..+1023
    __shared__ float tile[64][69];
    const float* s = w0 + (size_t)z * 1024 * H_;
    unsigned short* d = w0t + (size_t)z * 1024;
    int r0 = blockIdx.x * 64, c0 = blockIdx.y * 64;
    int col4 = (tid & 15) * 4, row = tid >> 4;
    #pragma unroll
    for (int it = 0; it < 4; it++) {
        int r = it * 16 + row;
        float4 v = *(const float4*)(s + (size_t)(r0 + r) * 1024 + c0 + col4);
        *(float4*)(&tile[r][col4]) = v;
    }
    __syncthreads();
    #pragma unroll
    for (int it = 0; it < 2; it++) {
        int slot = it * 256 + tid;
        int c = slot >> 3, chunk = slot & 7;
        int r = chunk * 8;
        uint4 vv;
        vv.x = (unsigned int)f2b(tile[r + 0][c]) | ((unsigned int)f2b(tile[r + 1][c]) << 16);
        vv.y = (unsigned int)f2b(tile[r + 2][c]) | ((unsigned int)f2b(tile[r + 3][c]) << 16);
        vv.z = (unsigned int)f2b(tile[r + 4][c]) | ((unsigned int)f2b(tile[r + 5][c]) << 16);
        vv.w = (unsigned int)f2b(tile[r + 6][c]) | ((unsigned int)f2b(tile[r + 7][c]) << 16);
        *(uint4*)(d + (size_t)(c0 + c) * K3_ + r0 + r) = vv;
    }
}

// ---- shared device body: Gaussian weights for row m given spans ----
static __device__ __forceinline__ void weights_body(int m, float s, float e,
                                                    const float* __restrict__ vmask,
                                                    float ls_s, float ls_e,
                                                    float sw_s, float sw_e,
                                                    const float* __restrict__ msc,
                                                    unsigned short* __restrict__ wt2,
                                                    float* r0, float* r1) {
    int b = m / Q_, q = m - b * Q_;
    int tid = threadIdx.x;
    float width = fmaxf(e - s, 1e-6f);
    const float min_sig = 1.0f / (4.0f * (float)L_);
    float sig_s = fmaxf(expf(ls_s + sw_s * width + msc[MS_TOS + b]), min_sig);
    float sig_e = fmaxf(expf(ls_e + sw_e * width + msc[MS_TOE + b]), min_sig);
    float inv_s = 1.0f / sig_s, inv_e = 1.0f / sig_e;

    float wsv[4], wev[4], sumS = 0.f, sumE = 0.f;
    #pragma unroll
    for (int k = 0; k < 4; k++) {
        int l = tid + k * 256;
        float t = (float)l * (1.0f / 1023.0f);
        float mk = vmask[b * L_ + l];
        float ds = (t - s) * inv_s, de = (t - e) * inv_e;
        float a = expf(-0.5f * ds * ds) * mk;
        float c = expf(-0.5f * de * de) * mk;
        wsv[k] = a; wev[k] = c; sumS += a; sumE += c;
    }
    r0[tid] = sumS; r1[tid] = sumE; __syncthreads();
    for (int off = 128; off > 0; off >>= 1) {
        if (tid < off) { r0[tid] += r0[tid + off]; r1[tid] += r1[tid + off]; }
        __syncthreads();
    }
    float iS = 1.0f / fmaxf(r0[0], 1e-8f);
    float iE = 1.0f / fmaxf(r1[0], 1e-8f);
    unsigned short* wq = wt2 + ((size_t)b * QQ_ + q) * L_;
    unsigned short* we = wt2 + ((size_t)b * QQ_ + Q_ + q) * L_;
    #pragma unroll
    for (int k = 0; k < 4; k++) {
        int l = tid + k * 256;
        wq[l] = f2b(wsv[k] * iS);
        we[l] = f2b(wev[k] * iE);
    }
}

// ==== launch 2: weights(pass0) [bid<1280] + txt_mlp0 [bid>=1280] ====
__global__ __launch_bounds__(256) void k_stage2(const float* __restrict__ vmask,
                                                const float* __restrict__ p_ls_s,
                                                const float* __restrict__ p_ls_e,
                                                const float* __restrict__ p_sw_s,
                                                const float* __restrict__ p_sw_e,
                                                const float* __restrict__ msc,
                                                unsigned short* __restrict__ wt2,
                                                const unsigned short* __restrict__ txtb,
                                                const unsigned short* __restrict__ w0t,
                                                unsigned short* __restrict__ txtp) {
    int bid = blockIdx.x;
    if (bid < M_) {
        __shared__ float r0[256], r1[256];
        int m = bid;
        weights_body(m, msc[MS_START + m], msc[MS_END + m], vmask,
                     p_ls_s[0], p_ls_e[0], p_sw_s[0], p_sw_e[0], msc, wt2, r0, r1);
        return;
    }
    int t = bid - M_;                    // 0..127
    int nIdx = t & 15, mIdx = (t >> 4) & 1, kIdx = t >> 5;
    int wv = threadIdx.x >> 6, lane = threadIdx.x & 63;
    int ml = lane & 15, kg = lane >> 4;
    int mbase = mIdx * 16;
    int nbase = nIdx * 64 + wv * 16;
    int kz = kIdx * 256;
    const unsigned short* ap = txtb + ((size_t)(mbase + ml) * H_ + kz + kg * 8);
    const unsigned short* bp = w0t + ((size_t)(nbase + ml) * K3_ + JK_ + kz + kg * 8);
    f4 acc = (f4){0.f, 0.f, 0.f, 0.f};
    #pragma unroll
    for (int k0 = 0; k0 < 256; k0 += 32) {
        bf8 a = *(const bf8*)(ap + k0);
        bf8 bb = *(const bf8*)(bp + k0);
        acc = __builtin_amdgcn_mfma_f32_16x16x32_bf16(a, bb, acc, 0, 0, 0);
    }
    unsigned short* pp = txtp + (size_t)kIdx * B_ * H_;
    int n = nbase + ml;
    #pragma unroll
    for (int r = 0; r < 4; r++) {
        int m = mbase + kg * 4 + r;
        pp[(size_t)m * H_ + n] = f2b(acc[r]);
    }
}

// ==== pool via MFMA, native-vid LDS staging (no pre-transpose) ====
// grid (B, 16); block 512 = 8 waves: wave = (hsub 0..3, half 0..1)
// A = wt2[qq][l] (global, k-contig), B = vid tile (LDS, transposed in staging)
// C[q][h]; halves combined + transposed via fp32 LDS, stored 128B-contiguous.
__global__ __launch_bounds__(512) void k_pool_mfma(const float* __restrict__ vid,
                                                   const unsigned short* __restrict__ wt2,
                                                   unsigned short* __restrict__ joint) {
    int b = blockIdx.x, ht = blockIdx.y;
    int tid = threadIdx.x;
    int wv = tid >> 6, lane = tid & 63;
    int hsub = wv & 3, half = wv >> 2;
    int ml = lane & 15, kg = lane >> 4;
    int h0 = ht * 64;

    __shared__ __align__(16) unsigned short tileT[2][2][64][40]; // [half][buf][h][l+pad] 20.0 KB
    __shared__ float cmb[80][68];                                 // 21.25 KB

    // staging mapping: each half's 256 threads
    int st = tid & 255;
    int sl = st >> 3;                 // l_local 0..31
    int sh8 = (st & 7) * 8;           // h8: 8 consecutive h per thread
    const float* vbase = vid + ((size_t)b * L_ + half * 512) * H_ + h0;

    const unsigned short* ap = wt2 + ((size_t)b * QQ_ + ml) * L_ + half * 512 + kg * 8;

    f4 acc[5];
    #pragma unroll
    for (int t = 0; t < 5; t++) acc[t] = (f4){0.f, 0.f, 0.f, 0.f};

    // stage chunk 0 into buf 0
    {
        const float* src = vbase + (size_t)sl * H_ + sh8;
        float4 v0 = *(const float4*)(src);
        float4 v1 = *(const float4*)(src + 4);
        unsigned short* dst = &tileT[half][0][0][0];
        dst[(sh8 + 0) * 40 + sl] = f2b(v0.x);
        dst[(sh8 + 1) * 40 + sl] = f2b(v0.y);
        dst[(sh8 + 2) * 40 + sl] = f2b(v0.z);
        dst[(sh8 + 3) * 40 + sl] = f2b(v0.w);
        dst[(sh8 + 4) * 40 + sl] = f2b(v1.x);
        dst[(sh8 + 5) * 40 + sl] = f2b(v1.y);
        dst[(sh8 + 6) * 40 + sl] = f2b(v1.z);
        dst[(sh8 + 7) * 40 + sl] = f2b(v1.w);
    }
    __syncthreads();

    for (int c = 0; c < 16; c++) {
        int buf = c & 1;
        if (c < 15) {   // prefetch chunk c+1 into the other buffer
            const float* src = vbase + (size_t)((c + 1) * 32 + sl) * H_ + sh8;
            float4 v0 = *(const float4*)(src);
            float4 v1 = *(const float4*)(src + 4);
            unsigned short* dst = &tileT[half][buf ^ 1][0][0];
            dst[(sh8 + 0) * 40 + sl] = f2b(v0.x);
            dst[(sh8 + 1) * 40 + sl] = f2b(v0.y);
            dst[(sh8 + 2) * 40 + sl] = f2b(v0.z);
            dst[(sh8 + 3) * 40 + sl] = f2b(v0.w);
            dst[(sh8 + 4) * 40 + sl] = f2b(v1.x);
            dst[(sh8 + 5) * 40 + sl] = f2b(v1.y);
            dst[(sh8 + 6) * 40 + sl] = f2b(v1.z);
            dst[(sh8 + 7) * 40 + sl] = f2b(v1.w);
        }
        // compute on buf
        bf8 bfrag = *(const bf8*)(&tileT[half][buf][hsub * 16 + ml][kg * 8]);
        int l0 = c * 32;
        #pragma unroll
        for (int t = 0; t < 5; t++) {
            bf8 afr = *(const bf8*)(ap + (size_t)t * 16 * L_ + l0);
            acc[t] = __builtin_amdgcn_mfma_f32_16x16x32_bf16(afr, bfrag, acc[t], 0, 0, 0);
        }
        __syncthreads();
    }

    // combine halves: half1 dumps, half0 adds and writes back
    if (half == 1) {
        #pragma unroll
        for (int t = 0; t < 5; t++)
            #pragma unroll
            for (int r = 0; r < 4; r++)
                cmb[t * 16 + kg * 4 + r][hsub * 16 + ml] = acc[t][r];
    }
    __syncthreads();
    if (half == 0) {
        #pragma unroll
        for (int t = 0; t < 5; t++)
            #pragma unroll
            for (int r = 0; r < 4; r++)
                cmb[t * 16 + kg * 4 + r][hsub * 16 + ml] += acc[t][r];
    }
    __syncthreads();
    // cooperative store: 80 qq-rows x 64 h, 128B contiguous per row
    for (int idx = tid; idx < 640; idx += 512) {
        int qq = idx >> 3, h8 = (idx & 7) * 8;
        const float* cr = &cmb[qq][h8];
        uint4 vv;
        vv.x = (unsigned int)f2b(cr[0]) | ((unsigned int)f2b(cr[1]) << 16);
        vv.y = (unsigned int)f2b(cr[2]) | ((unsigned int)f2b(cr[3]) << 16);
        vv.z = (unsigned int)f2b(cr[4]) | ((unsigned int)f2b(cr[5]) << 16);
        vv.w = (unsigned int)f2b(cr[6]) | ((unsigned int)f2b(cr[7]) << 16);
        int row = b * Q_ + (qq >= Q_ ? qq - Q_ : qq);
        int col = (qq >= Q_ ? H_ : 0) + h0 + h8;
        *(uint4*)(joint + (size_t)row * JK_ + col) = vv;
    }
}

// ==== MLP0 via MFMA over feat-K (2048), K-split x4, + txtpart in epilogue ====
// grid (20, 16, 4); block 256 = 4 waves; wave: 16 m x 64 n, k-range 512
__global__ __launch_bounds__(256) void k_mlp0_mfma(const unsigned short* __restrict__ joint,
                                                   const unsigned short* __restrict__ w0t,
                                                   const unsigned short* __restrict__ txtp,
                                                   unsigned short* __restrict__ part) {
    int wv = threadIdx.x >> 6, lane = threadIdx.x & 63;
    int ml = lane & 15, kg = lane >> 4;
    int mbase = blockIdx.x * 64 + wv * 16;
    int nbase = blockIdx.y * 64;
    int kbase = blockIdx.z * 512;
    const unsigned short* ap = joint + ((size_t)(mbase + ml) * JK_ + kbase + kg * 8);
    const unsigned short* bp = w0t + ((size_t)(nbase + ml) * K3_ + kbase + kg * 8);
    f4 acc[4];
    #pragma unroll
    for (int t = 0; t < 4; t++) acc[t] = (f4){0.f, 0.f, 0.f, 0.f};

    #pragma unroll 4
    for (int k0 = 0; k0 < 512; k0 += 32) {
        bf8 a = *(const bf8*)(ap + k0);
        #pragma unroll
        for (int t = 0; t < 4; t++) {
            bf8 bb = *(const bf8*)(bp + (size_t)t * 16 * K3_ + k0);
            acc[t] = __builtin_amdgcn_mfma_f32_16x16x32_bf16(a, bb, acc[t], 0, 0, 0);
        }
    }
    const unsigned short* tp = txtp + (size_t)blockIdx.z * B_ * H_;
    unsigned short* pp = part + (size_t)blockIdx.z * M_ * H_;
    #pragma unroll
    for (int t = 0; t < 4; t++) {
        int n = nbase + t * 16 + ml;
        #pragma unroll
        for (int r = 0; r < 4; r++) {
            int m = mbase + kg * 4 + r;
            int b = m / Q_;
            float v = acc[t][r] + b2f16(tp[(size_t)b * H_ + n]);
            pp[(size_t)m * H_ + n] = f2b(v);
        }
    }
}

// ==== MLP1 + span update + outputs (+ weights for NEXT pass if do_weights) ====
__global__ __launch_bounds__(256) void k_mlp1w(const float* __restrict__ w1,
                                               const float* __restrict__ b0,
                                               const float* __restrict__ b1,
                                               const unsigned short* __restrict__ part,
                                               float* __restrict__ msc,
                                               float* __restrict__ out, int pass,
                                               int do_weights,
                                               const float* __restrict__ vmask,
                                               const float* __restrict__ p_ls_s,
                                               const float* __restrict__ p_ls_e,
                                               const float* __restrict__ p_sw_s,
                                               const float* __restrict__ p_sw_e,
                                               unsigned short* __restrict__ wt2) {
    int m = blockIdx.x, tid = threadIdx.x;
    int k4 = tid * 4;
    float4 bb = *(const float4*)(b0 + k4);
    float h0 = bb.x, h1 = bb.y, h2 = bb.z, h3 = bb.w;
    #pragma unroll
    for (int z = 0; z < 4; z++) {
        uint2 u = *(const uint2*)(part + (size_t)z * M_ * H_ + (size_t)m * H_ + k4);
        h0 += blo(u.x); h1 += bhi(u.x);
        h2 += blo(u.y); h3 += bhi(u.y);
    }
    h0 = fmaxf(h0, 0.f); h1 = fmaxf(h1, 0.f);
    h2 = fmaxf(h2, 0.f); h3 = fmaxf(h3, 0.f);
    float4 wa = *(const float4*)(w1 + 2 * k4);
    float4 wb = *(const float4*)(w1 + 2 * k4 + 4);
    float p0 = h0 * wa.x + h1 * wa.z + h2 * wb.x + h3 * wb.z;
    float p1 = h0 * wa.y + h1 * wa.w + h2 * wb.y + h3 * wb.w;

    __shared__ float r0[256], r1[256];
    __shared__ float sh_s, sh_e;
    r0[tid] = p0; r1[tid] = p1; __syncthreads();
    for (int off = 128; off > 0; off >>= 1) {
        if (tid < off) { r0[tid] += r0[tid + off]; r1[tid] += r1[tid + off]; }
        __syncthreads();
    }
    if (tid == 0) {
        float d0 = tanhf(r0[0] + b1[0]) * 0.1f;
        float d1 = tanhf(r1[0] + b1[1]) * 0.1f;
        float s = fminf(fmaxf(msc[MS_START + m] + d0, 0.f), 1.f);
        float e = fminf(fmaxf(msc[MS_END + m] + d1, 0.f), 1.f);
        msc[MS_START + m] = s;
        msc[MS_END + m] = e;
        sh_s = s; sh_e = e;
        float cen = 0.5f * (s + e);
        float wid = fmaxf(e - s, 1e-6f);
        out[2560 + (size_t)(pass * M_ + m) * 2 + 0] = cen;
        out[2560 + (size_t)(pass * M_ + m) * 2 + 1] = wid;
        if (pass == 1) { out[2 * m + 0] = cen; out[2 * m + 1] = wid; }
    }
    __syncthreads();
    if (do_weights) {
        weights_body(m, sh_s, sh_e, vmask,
                     p_ls_s[0], p_ls_e[0], p_sw_s[0], p_sw_e[0], msc, wt2, r0, r1);
    }
}

extern "C" void kernel_launch(void* const* d_in, const int* in_sizes, int n_in,
                              void* d_out, int out_size, void* d_ws, size_t ws_size,
                              hipStream_t stream) {
    const float* spans = (const float*)d_in[0];
    const float* vid   = (const float*)d_in[1];
    const float* vmask = (const float*)d_in[2];
    const float* txt   = (const float*)d_in[3];
    const float* ls_s  = (const float*)d_in[4];
    const float* ls_e  = (const float*)d_in[5];
    const float* sw_s  = (const float*)d_in[6];
    const float* sw_e  = (const float*)d_in[7];
    const float* pw    = (const float*)d_in[8];
    const float* pb    = (const float*)d_in[9];
    const float* w0    = (const float*)d_in[10];
    const float* b0    = (const float*)d_in[11];
    const float* w1    = (const float*)d_in[12];
    const float* b1    = (const float*)d_in[13];
    char* wsb = (char*)d_ws;
    unsigned short* w0t   = (unsigned short*)(wsb + OB_W0T);
    unsigned short* wt2   = (unsigned short*)(wsb + OB_WT2);
    unsigned short* joint = (unsigned short*)(wsb + OB_JOINT);
    unsigned short* part  = (unsigned short*)(wsb + OB_PART);
    unsigned short* txtb  = (unsigned short*)(wsb + OB_TXTB);
    unsigned short* txtp  = (unsigned short*)(wsb + OB_TXTP);
    float* msc = (float*)(wsb + OB_MISC);
    float* out = (float*)d_out;

    hipLaunchKernelGGL(k_setup, dim3(16, 16, 4), dim3(256), 0, stream,
                       w0, w0t, txt, pw, pb, spans, txtb, msc);
    hipLaunchKernelGGL(k_stage2, dim3(M_ + 128), dim3(256), 0, stream,
                       vmask, ls_s, ls_e, sw_s, sw_e, msc, wt2, txtb, w0t, txtp);
    for (int p = 0; p < 2; p++) {
        hipLaunchKernelGGL(k_pool_mfma, dim3(B_, 16), dim3(512), 0, stream, vid, wt2, joint);
        hipLaunchKernelGGL(k_mlp0_mfma, dim3(20, 16, 4), dim3(256), 0, stream,
                           joint, w0t, txtp, part);
        hipLaunchKernelGGL(k_mlp1w, dim3(M_), dim3(256), 0, stream,
                           w1, b0, b1, part, msc, out, p, (p == 0) ? 1 : 0,
                           vmask, ls_s, ls_e, sw_s, sw_e, wt2);
    }
}